// Round 3
// baseline (444.673 us; speedup 1.0000x reference)
//
#include <hip/hip_runtime.h>
#include <hip/hip_bf16.h>

typedef __attribute__((ext_vector_type(8))) short short8;   // 8 bf16 (4 VGPRs)
typedef __attribute__((ext_vector_type(4))) short short4_t; // 8 B
typedef __attribute__((ext_vector_type(4))) float f32x4;    // MFMA 16x16 acc

union S8u { short8 v; short4_t h[2]; };
union P8u { unsigned char b[8]; long v; };

static __device__ __forceinline__ short f2b(float f) {
    union { float f; unsigned u; } v; v.f = f;
    unsigned r = v.u + 0x7FFFu + ((v.u >> 16) & 1u);   // RNE
    return (short)(r >> 16);
}
static __device__ __forceinline__ unsigned char f2fp8(float f) {
    return (unsigned char)(__builtin_amdgcn_cvt_pk_fp8_f32(f, f, 0, false) & 0xff);
}

// ---------------------------------------------------------------------------
// prep_w: fragment buffers, one THREAD per (tile,lane) -> 8 elems.
//  tiles: [0,364) AWF  (g*13+kt):  A^T*W1^T [m=g*16+lm][n=kt*32+quad*8+j]
//         [364,414) W2F (jt*2+kh): W2[f=kh*32+quad*8+j][jc=jt*16+lm]
//         [414,422) W3F (ut*2+kh): W3[f][u=ut*16+lm]
//  then Ab2[448 m][448 j] bytes = (A[m][j] != 0), zero-padded (m,j >= 400).
// grid 890 x 256 (422*64 + 448*448 = 227712 threads)
// ---------------------------------------------------------------------------
__global__ __launch_bounds__(256) void prep_w(
    const float* __restrict__ A, const float* __restrict__ W1,
    const float* __restrict__ W2, const float* __restrict__ W3,
    short* __restrict__ AWF, short* __restrict__ W2F,
    short* __restrict__ W3F, unsigned char* __restrict__ Ab2)
{
    int t = blockIdx.x * 256 + threadIdx.x;
    if (t < 422 * 64) {
        int tile = t >> 6, lane = t & 63, lm = lane & 15, quad = lane >> 4;
        short8 o;
        if (tile < 364) {
            int kt = tile % 13, g = tile / 13;
            int m = g * 16 + lm;
#pragma unroll
            for (int j = 0; j < 8; ++j) {
                int n = kt * 32 + quad * 8 + j;
                float v = (m < 400 && n < 400) ? A[n * 400 + m] * W1[n * 400 + m] : 0.f;
                o[j] = f2b(v);
            }
            *(short8*)(AWF + tile * 512 + lane * 8) = o;
        } else if (tile < 414) {
            int t2 = tile - 364;
            int kh = t2 & 1, jt = t2 >> 1;
            int jc = jt * 16 + lm;
#pragma unroll
            for (int j = 0; j < 8; ++j) {
                int f = kh * 32 + quad * 8 + j;
                o[j] = f2b(W2[f * 400 + jc]);
            }
            *(short8*)(W2F + t2 * 512 + lane * 8) = o;
        } else {
            int t3 = tile - 414;
            int kh = t3 & 1, ut = t3 >> 1;
            int u = ut * 16 + lm;
#pragma unroll
            for (int j = 0; j < 8; ++j) {
                int f = kh * 32 + quad * 8 + j;
                o[j] = f2b(W3[f * 64 + u]);
            }
            *(short8*)(W3F + t3 * 512 + lane * 8) = o;
        }
    } else {
        int o = t - 27008;
        if (o < 448 * 448) {
            int m = o / 448, j = o - m * 448;
            Ab2[o] = (m < 400 && j < 400 && A[m * 400 + j] != 0.f) ? 1 : 0;
        }
    }
}

// ---------------------------------------------------------------------------
// prep_xt: xF / xF8 fragment-linear, no LDS. One wave per tile; thread
// gathers 8 elems via 8 wave-coalesced dword loads, writes 16B + 8B.
// grid 480*13 blocks; block = (bt, kt), 4 waves = ft 0..3.
// ---------------------------------------------------------------------------
__global__ __launch_bounds__(256) void prep_xt(
    const float* __restrict__ x, short* __restrict__ xF,
    unsigned char* __restrict__ xF8)
{
    int bt = blockIdx.x / 13, kt = blockIdx.x % 13;
    int tid = threadIdx.x, lane = tid & 63, ft = tid >> 6;
    int lm = lane & 15, quad = lane >> 4;
    const float* xs = x + (size_t)bt * 25600;
    int tile = kt * 4 + ft;
    int f = ft * 16 + lm;
    short8 ob; P8u p8;
#pragma unroll
    for (int j = 0; j < 8; ++j) {
        int n = kt * 32 + quad * 8 + j;
        float v = (n < 400) ? xs[(size_t)n * 64 + f] : 0.f;
        ob[j] = f2b(v);
        p8.b[j] = f2fp8(v);
    }
    size_t o = (size_t)bt * 26624 + tile * 512 + lane * 8;
    *(short8*)(xF + o) = ob;
    *(long*)(xF8 + o) = p8.v;
}

// ---------------------------------------------------------------------------
// dgc_mfma v7: v6 exploded into 1-WAVE BLOCKS. The 4 waves of the old
// 256-thread block shared NOTHING (no __syncthreads; featS/attnS8 strips
// wave-private) — the fat block just forced the scheduler to co-allocate
// 37.9 KB LDS + 4 waves atomically, capping co-residency at ~2.3 blocks/CU
// (Occupancy 29%, latency-bound: MFMA 10% / VALU 22% / HBM 4%).
// Now: 64-thread blocks, 9.4 KB LDS (17 blocks/CU by LDS),
// launch_bounds(64,4) caps regs at 128 (Phase B peak live ~95) -> 16
// waves/CU by VGPR. ~1.7x TLP for the same L2-latency-dominated chain.
// grid 13440 = 8 XCD * 60 bt * 28 row-groups (XCD-contiguous bt preserved).
// ---------------------------------------------------------------------------
__global__ __launch_bounds__(64, 4) void dgc_mfma(
    const float* __restrict__ b1p, const float* __restrict__ b2p,
    const unsigned* __restrict__ Ab2,
    const short* __restrict__ AWF, const short* __restrict__ W2F,
    const short* __restrict__ W3F, const short* __restrict__ xF,
    const unsigned char* __restrict__ xF8,
    const float* __restrict__ taW1, const float* __restrict__ taW3,
    short* __restrict__ y, float* __restrict__ rhs, float* __restrict__ r1)
{
    int bid = blockIdx.x;
    int c = bid & 7, jj = bid >> 3;     // c = XCD (round-robin), jj in [0,1680)
    int bt = c * 60 + jj / 28;          // 60 consecutive bt per XCD
    int g  = jj % 28;                   // 16-row group: rows [g*16, g*16+16)
    int lane = threadIdx.x;
    int lm = lane & 15, quad = lane >> 4;

    __shared__ __align__(16) char  attnS8[16 * 440];
    __shared__ __align__(16) short featS[16 * 72];
    __shared__ __align__(16) float invS[16];

    {   // zero pad cols [400,440) of own strip
        *(long*)&attnS8[lm * 440 + 400 + quad * 8] = 0;
        if (quad == 0) *(long*)&attnS8[lm * 440 + 432] = 0;
    }

    const short* xtb = xF + (size_t)bt * 26624 + lane * 8;
    const unsigned char* xt8b = xF8 + (size_t)bt * 26624 + lane * 8;

    // ---- Phase A: feat stripe [16 x 64] = AWT @ x, batched 2 kt ----
    f32x4 fa[4];
#pragma unroll
    for (int i = 0; i < 4; ++i) fa[i] = (f32x4){0.f, 0.f, 0.f, 0.f};
    const short* awf = AWF + (size_t)g * 13 * 512 + lane * 8;
#pragma unroll
    for (int kb = 0; kb < 12; kb += 2) {
        short8 af0 = *(const short8*)(awf + kb * 512);
        short8 af1 = *(const short8*)(awf + (kb + 1) * 512);
        short8 bf[8];
#pragma unroll
        for (int ft = 0; ft < 4; ++ft) {
            bf[ft]     = *(const short8*)(xtb + (kb * 4 + ft) * 512);
            bf[4 + ft] = *(const short8*)(xtb + ((kb + 1) * 4 + ft) * 512);
        }
#pragma unroll
        for (int ft = 0; ft < 4; ++ft) {
            fa[ft] = __builtin_amdgcn_mfma_f32_16x16x32_bf16(af0, bf[ft], fa[ft], 0, 0, 0);
            fa[ft] = __builtin_amdgcn_mfma_f32_16x16x32_bf16(af1, bf[4 + ft], fa[ft], 0, 0, 0);
        }
    }
    {   // kt = 12 tail
        short8 af = *(const short8*)(awf + 12 * 512);
        short8 bf[4];
#pragma unroll
        for (int ft = 0; ft < 4; ++ft)
            bf[ft] = *(const short8*)(xtb + (48 + ft) * 512);
#pragma unroll
        for (int ft = 0; ft < 4; ++ft)
            fa[ft] = __builtin_amdgcn_mfma_f32_16x16x32_bf16(af, bf[ft], fa[ft], 0, 0, 0);
    }
#pragma unroll
    for (int ft = 0; ft < 4; ++ft)
#pragma unroll
        for (int r = 0; r < 4; ++r)
            featS[(quad * 4 + r) * 72 + ft * 16 + lm] = f2b(fa[ft][r]);

    // ---- Phase B (swapped): D' = W2^T @ feat^T, chunked 5 jt ----
    // Lane holds D'[j = jt*16+quad*4+r][m = g*16+lm] = dense[m][j].
    short8 a0 = *(const short8*)&featS[lm * 72 + quad * 8];
    short8 a1 = *(const short8*)&featS[lm * 72 + 32 + quad * 8];
    int m = g * 16 + lm;                             // lane's output row
    const unsigned* ab2 = Ab2 + (size_t)m * 112;     // Ab2[m][j] dwords
    float s_row = 0.f;
#pragma unroll
    for (int jb = 0; jb < 25; jb += 5) {
        short8 bf[10];
#pragma unroll
        for (int q = 0; q < 5; ++q) {
            bf[2 * q]     = *(const short8*)(W2F + ((jb + q) * 2 + 0) * 512 + lane * 8);
            bf[2 * q + 1] = *(const short8*)(W2F + ((jb + q) * 2 + 1) * 512 + lane * 8);
        }
        f32x4 da5[5];
#pragma unroll
        for (int q = 0; q < 5; ++q) {
            da5[q] = (f32x4){0.f, 0.f, 0.f, 0.f};
            da5[q] = __builtin_amdgcn_mfma_f32_16x16x32_bf16(bf[2 * q],     a0, da5[q], 0, 0, 0);
            da5[q] = __builtin_amdgcn_mfma_f32_16x16x32_bf16(bf[2 * q + 1], a1, da5[q], 0, 0, 0);
        }
#pragma unroll
        for (int q = 0; q < 5; ++q) {
            int jt = jb + q;
            float4 b1v = *(const float4*)(b1p + jt * 16 + quad * 4);
            unsigned mv = ab2[jt * 4 + quad];
            float e0 = (mv & 255u)         ? __expf(da5[q][0] + b1v.x) : 0.f;
            float e1 = ((mv >> 8) & 255u)  ? __expf(da5[q][1] + b1v.y) : 0.f;
            float e2 = ((mv >> 16) & 255u) ? __expf(da5[q][2] + b1v.z) : 0.f;
            float e3 = ((mv >> 24) & 255u) ? __expf(da5[q][3] + b1v.w) : 0.f;
            s_row += (e0 + e1) + (e2 + e3);
            int pk = __builtin_amdgcn_cvt_pk_fp8_f32(e0, e1, 0, false);
            pk = __builtin_amdgcn_cvt_pk_fp8_f32(e2, e3, pk, true);
            *(int*)&attnS8[lm * 440 + jt * 16 + quad * 4] = pk;
        }
    }
    s_row += __shfl_xor(s_row, 16);
    s_row += __shfl_xor(s_row, 32);
    float invv = (s_row > 0.f) ? (1.f / s_row) : 0.f;
    if (quad == 0) invS[lm] = invv;

    // ---- Phase D: nodef stripe [16 x 64] = attn_unnorm @ x (fp8) ----
    f32x4 na[4];
#pragma unroll
    for (int i = 0; i < 4; ++i) na[i] = (f32x4){0.f, 0.f, 0.f, 0.f};
    const char* at_row = attnS8 + lm * 440 + quad * 8;
#pragma unroll
    for (int kb = 0; kb < 12; kb += 2) {
        long af0 = *(const long*)(at_row + kb * 32);
        long af1 = *(const long*)(at_row + (kb + 1) * 32);
        long bf[8];
#pragma unroll
        for (int ft = 0; ft < 4; ++ft) {
            bf[ft]     = *(const long*)(xt8b + (kb * 4 + ft) * 512);
            bf[4 + ft] = *(const long*)(xt8b + ((kb + 1) * 4 + ft) * 512);
        }
#pragma unroll
        for (int ft = 0; ft < 4; ++ft) {
            na[ft] = __builtin_amdgcn_mfma_f32_16x16x32_fp8_fp8(af0, bf[ft], na[ft], 0, 0, 0);
            na[ft] = __builtin_amdgcn_mfma_f32_16x16x32_fp8_fp8(af1, bf[4 + ft], na[ft], 0, 0, 0);
        }
    }
    {   // kt = 12 tail
        long af = *(const long*)(at_row + 12 * 32);
        long bf[4];
#pragma unroll
        for (int ft = 0; ft < 4; ++ft)
            bf[ft] = *(const long*)(xt8b + (48 + ft) * 512);
#pragma unroll
        for (int ft = 0; ft < 4; ++ft)
            na[ft] = __builtin_amdgcn_mfma_f32_16x16x32_fp8_fp8(af, bf[ft], na[ft], 0, 0, 0);
    }
#pragma unroll
    for (int ft = 0; ft < 4; ++ft)
#pragma unroll
        for (int r = 0; r < 4; ++r)
            featS[(quad * 4 + r) * 72 + ft * 16 + lm] = f2b(na[ft][r]);

    // ---- Phase E: y stripe [16 x 64] = nodef @ W3, then * inv_s + b2 ----
    f32x4 ya[4];
#pragma unroll
    for (int i = 0; i < 4; ++i) ya[i] = (f32x4){0.f, 0.f, 0.f, 0.f};
    short8 nf0 = *(const short8*)&featS[lm * 72 + quad * 8];
    short8 nf1 = *(const short8*)&featS[lm * 72 + 32 + quad * 8];
    {
        short8 wb[8];
#pragma unroll
        for (int ut = 0; ut < 4; ++ut) {
            wb[2 * ut]     = *(const short8*)(W3F + (ut * 2 + 0) * 512 + lane * 8);
            wb[2 * ut + 1] = *(const short8*)(W3F + (ut * 2 + 1) * 512 + lane * 8);
        }
#pragma unroll
        for (int ut = 0; ut < 4; ++ut) {
            ya[ut] = __builtin_amdgcn_mfma_f32_16x16x32_bf16(nf0, wb[2 * ut], ya[ut], 0, 0, 0);
            ya[ut] = __builtin_amdgcn_mfma_f32_16x16x32_bf16(nf1, wb[2 * ut + 1], ya[ut], 0, 0, 0);
        }
    }

    // ---- Epilogue: deferred softmax scale, y store + rhs + r1 partials ----
    int mrb = g * 16 + quad * 4;                    // 4-aligned
    float4 inv4 = *(const float4*)&invS[quad * 4];  // rows mrb..mrb+3
    float invr[4] = {inv4.x, inv4.y, inv4.z, inv4.w};
    float yv[4][4];
#pragma unroll
    for (int ut = 0; ut < 4; ++ut) {
        int u = ut * 16 + lm;
        float b2v = b2p[u];
#pragma unroll
        for (int r = 0; r < 4; ++r) {
            yv[ut][r] = ya[ut][r] * invr[r] + b2v;
            int mrow = mrb + r;
            if (mrow < 400)
                y[((size_t)bt * 400 + mrow) * 64 + u] = f2b(yv[ut][r]);
        }
    }
    // rhs[bt, mrb+r] = sum_u yv*taW3[u] (reduce over 16 lanes of quad)
    float w3r[4];
#pragma unroll
    for (int ut = 0; ut < 4; ++ut) w3r[ut] = taW3[ut * 16 + lm];
    float rv[4];
#pragma unroll
    for (int r = 0; r < 4; ++r) {
        float v = yv[0][r] * w3r[0] + yv[1][r] * w3r[1] +
                  yv[2][r] * w3r[2] + yv[3][r] * w3r[3];
        v += __shfl_xor(v, 1);
        v += __shfl_xor(v, 2);
        v += __shfl_xor(v, 4);
        v += __shfl_xor(v, 8);
        rv[r] = v;
    }
    if (lm == 0 && mrb < 400)
        *(float4*)(rhs + (size_t)bt * 400 + mrb) = make_float4(rv[0], rv[1], rv[2], rv[3]);
    // r1[bt, u] += sum_rows yv*taW1[row] (reduce over quads, atomic)
    float p[4] = {0.f, 0.f, 0.f, 0.f};
#pragma unroll
    for (int r = 0; r < 4; ++r) {
        int mrow = mrb + r;
        if (mrow < 400) {
            float w1v = taW1[mrow];
#pragma unroll
            for (int ut = 0; ut < 4; ++ut) p[ut] += yv[ut][r] * w1v;
        }
    }
#pragma unroll
    for (int ut = 0; ut < 4; ++ut) {
        p[ut] += __shfl_xor(p[ut], 16);
        p[ut] += __shfl_xor(p[ut], 32);
    }
    if (quad == 0) {
#pragma unroll
        for (int ut = 0; ut < 4; ++ut)
            atomicAdd(&r1[bt * 64 + ut * 16 + lm], p[ut]);
    }
}

// ---------------------------------------------------------------------------
// ta_lhs: lhs[bt,n] = sum_f r1[bt,f] * taW2[f,n]
// ---------------------------------------------------------------------------
__global__ __launch_bounds__(256) void ta_lhs(
    const float* __restrict__ r1, const float* __restrict__ taW2,
    float* __restrict__ lhs)
{
    int bt = blockIdx.x, tid = threadIdx.x;
    __shared__ float r1s[64];
    if (tid < 64) r1s[tid] = r1[bt * 64 + tid];
    __syncthreads();
    for (int n = tid; n < 400; n += 256) {
        float acc = 0.f;
#pragma unroll 8
        for (int f = 0; f < 64; ++f) acc += r1s[f] * taW2[f * 400 + n];
        lhs[bt * 400 + n] = acc;
    }
}

// ---------------------------------------------------------------------------
// ta_product: S[b,k,l] = sigmoid( lhs[b,k,:].rhs[b,l,:] + be[k,l] )
// ---------------------------------------------------------------------------
__global__ __launch_bounds__(256) void ta_product(
    const float* __restrict__ lhs, const float* __restrict__ rhs,
    const float* __restrict__ be, float* __restrict__ S)
{
    int kc = blockIdx.x, b = blockIdx.y, tid = threadIdx.x;
    if (tid >= 240) return;
    int k = kc * 4 + tid / 60;
    int l = tid % 60;
    const float4* lr = (const float4*)(lhs + (size_t)(b * 60 + k) * 400);
    const float4* rr = (const float4*)(rhs + (size_t)(b * 60 + l) * 400);
    float acc = 0.f;
    for (int q = 0; q < 100; ++q) {
        float4 a = lr[q], c = rr[q];
        acc += a.x * c.x + a.y * c.y + a.z * c.z + a.w * c.w;
    }
    float v = acc + be[k * 60 + l];
    S[b * 3600 + k * 60 + l] = 1.f / (1.f + __expf(-v));
}

// ---------------------------------------------------------------------------
// ta_softmax: E[b,j,l] = sum_k Ve[j,k]*S[b,k,l]; ker = softmax over j.
// ---------------------------------------------------------------------------
__global__ __launch_bounds__(256) void ta_softmax(
    const float* __restrict__ S, const float* __restrict__ Ve,
    float* __restrict__ ker)
{
    int b = blockIdx.x, tid = threadIdx.x;
    __shared__ float Ss[3600];
    __shared__ float Emat[3600];
    for (int i = tid; i < 3600; i += 256) Ss[i] = S[b * 3600 + i];
    __syncthreads();
    for (int p = tid; p < 3600; p += 256) {
        int j = p / 60, l = p % 60;
        float acc = 0.f;
        for (int k = 0; k < 60; ++k) acc += Ve[j * 60 + k] * Ss[k * 60 + l];
        Emat[p] = acc;
    }
    __syncthreads();
    for (int l = tid; l < 60; l += 256) {
        float mx = -1e30f;
        for (int j = 0; j < 60; ++j) mx = fmaxf(mx, Emat[j * 60 + l]);
        float s = 0.f;
        for (int j = 0; j < 60; ++j) s += __expf(Emat[j * 60 + l] - mx);
        float inv = 1.f / s;
        for (int j = 0; j < 60; ++j)
            ker[b * 3600 + j * 60 + l] = __expf(Emat[j * 60 + l] - mx) * inv;
    }
}

// ---------------------------------------------------------------------------
// ktf_prep: fragment-linear conv weights (unchanged).
// ---------------------------------------------------------------------------
__global__ __launch_bounds__(256) void ktf_prep(
    const float* __restrict__ tk, const float* __restrict__ rk,
    short* __restrict__ KTF)
{
    int i = blockIdx.x * 256 + threadIdx.x;      // [0, 98304)
    int j = i & 7, lane = (i >> 3) & 63, tile = i >> 9;   // tile in [0,192)
    int kkt = tile % 48, ng = tile / 48;
    int u = (ng >> 1) * 32 + (ng & 1) * 16 + (lane & 15);
    int kk = kkt * 32 + (lane >> 4) * 8 + j;
    int dt = kk >> 7, c = kk & 127;
    float v = (c < 64) ? tk[dt * 4096 + c * 64 + u]
                       : rk[dt * 4096 + (c - 64) * 64 + u];
    KTF[i] = f2b(v);
}

// ---------------------------------------------------------------------------
// fused_conv: time-mix + both temporal convs + softplus, bf16 MFMA.
// Conv K-loop batched 2 kkt for load overlap.
// ---------------------------------------------------------------------------
#define IN_S 132
__global__ __launch_bounds__(256, 4) void fused_conv(
    const short* __restrict__ y, const float* __restrict__ ker,
    const float* __restrict__ x, const short* __restrict__ KTF,
    const float* __restrict__ tb, const float* __restrict__ rb,
    float* __restrict__ out)
{
    int n = blockIdx.x, b = blockIdx.y;
    int tid = threadIdx.x, lane = tid & 63, w = tid >> 6;
    int m = lane & 15, quad = lane >> 4;
    int hm = w >> 1, hn = w & 1;

    __shared__ __align__(16) short In[75 * IN_S];
    __shared__ __align__(16) short kerT[64 * 72];
    __shared__ __align__(16) short ybT[64 * 72];

    for (int i = tid; i < 75 * IN_S; i += 256) In[i] = 0;
    for (int i = tid; i < 64 * 72; i += 256) { kerT[i] = 0; ybT[i] = 0; }
    __syncthreads();

    for (int i = tid; i < 3840; i += 256) {
        int t = i >> 6, u = i & 63;
        In[(t + 5) * IN_S + 64 + u] = f2b(x[((size_t)(b * 60 + t) * 400 + n) * 64 + u]);
    }
    for (int i = tid; i < 3840; i += 256) {
        int s = i >> 6, u = i & 63;
        ybT[u * 72 + s] = y[((size_t)(b * 60 + s) * 400 + n) * 64 + u];
    }
    for (int i = tid; i < 3600; i += 256) {
        int s = i / 60, t = i - s * 60;
        kerT[t * 72 + s] = f2b(ker[b * 3600 + s * 60 + t]);
    }
    __syncthreads();

    // ---- time-mix GEMM (M=64,N=64,K=64) ----
    f32x4 tacc[2][2];
#pragma unroll
    for (int a = 0; a < 2; ++a)
#pragma unroll
        for (int c = 0; c < 2; ++c) tacc[a][c] = (f32x4){0.f, 0.f, 0.f, 0.f};
#pragma unroll
    for (int k0 = 0; k0 < 64; k0 += 32) {
        short8 afr[2], bfr[2];
#pragma unroll
        for (int mt = 0; mt < 2; ++mt)
            afr[mt] = *(const short8*)&kerT[(hm * 32 + mt * 16 + m) * 72 + k0 + quad * 8];
#pragma unroll
        for (int nt = 0; nt < 2; ++nt)
            bfr[nt] = *(const short8*)&ybT[(hn * 32 + nt * 16 + m) * 72 + k0 + quad * 8];
#pragma unroll
        for (int mt = 0; mt < 2; ++mt)
#pragma unroll
            for (int nt = 0; nt < 2; ++nt)
                tacc[mt][nt] = __builtin_amdgcn_mfma_f32_16x16x32_bf16(
                    afr[mt], bfr[nt], tacc[mt][nt], 0, 0, 0);
    }
    __syncthreads();

#pragma unroll
    for (int mt = 0; mt < 2; ++mt)
#pragma unroll
        for (int nt = 0; nt < 2; ++nt)
#pragma unroll
            for (int r = 0; r < 4; ++r) {
                int t = hm * 32 + mt * 16 + quad * 4 + r;
                int u = hn * 32 + nt * 16 + m;
                if (t < 60) In[(t + 5) * IN_S + u] = f2b(tacc[mt][nt][r]);
            }
    __syncthreads();

    // ---- conv GEMM (M=64,N=64,K=1536), batched 2 kkt ----
    f32x4 acc[2][2];
#pragma unroll
    for (int a = 0; a < 2; ++a)
#pragma unroll
        for (int c = 0; c < 2; ++c) acc[a][c] = (f32x4){0.f, 0.f, 0.f, 0.f};

    const short* ktf0 = KTF + (size_t)(hn * 2 + 0) * 48 * 512 + lane * 8;
    const short* ktf1 = KTF + (size_t)(hn * 2 + 1) * 48 * 512 + lane * 8;

#pragma unroll 4
    for (int kb = 0; kb < 48; kb += 2) {
        S8u a0[2], a1[2];
        short8 b0[2], b1[2];
#pragma unroll
        for (int q = 0; q < 2; ++q) {
            int kk = (kb + q) * 32;
            int dt = kk >> 7, c0 = (kk & 127) + quad * 8;
            int i0 = (hm * 32 + m + dt) * IN_S + c0;
            int i1 = i0 + 16 * IN_S;
            a0[q].h[0] = *(const short4_t*)&In[i0];
            a0[q].h[1] = *(const short4_t*)&In[i0 + 4];
            a1[q].h[0] = *(const short4_t*)&In[i1];
            a1[q].h[1] = *(const short4_t*)&In[i1 + 4];
            b0[q] = *(const short8*)(ktf0 + (kb + q) * 512);
            b1[q] = *(const short8*)(ktf1 + (kb + q) * 512);
        }
#pragma unroll
        for (int q = 0; q < 2; ++q) {
            acc[0][0] = __builtin_amdgcn_mfma_f32_16x16x32_bf16(a0[q].v, b0[q], acc[0][0], 0, 0, 0);
            acc[0][1] = __builtin_amdgcn_mfma_f32_16x16x32_bf16(a0[q].v, b1[q], acc[0][1], 0, 0, 0);
            acc[1][0] = __builtin_amdgcn_mfma_f32_16x16x32_bf16(a1[q].v, b0[q], acc[1][0], 0, 0, 0);
            acc[1][1] = __builtin_amdgcn_mfma_f32_16x16x32_bf16(a1[q].v, b1[q], acc[1][1], 0, 0, 0);
        }
    }

    float bias[2];
#pragma unroll
    for (int nt = 0; nt < 2; ++nt) {
        int u = hn * 32 + nt * 16 + m;
        bias[nt] = tb[u] + rb[u];
    }
#pragma unroll
    for (int mt = 0; mt < 2; ++mt)
#pragma unroll
        for (int r = 0; r < 4; ++r) {
            int t = hm * 32 + mt * 16 + quad * 4 + r;
            if (t >= 60) continue;
#pragma unroll
            for (int nt = 0; nt < 2; ++nt) {
                int u = hn * 32 + nt * 16 + m;
                float v = acc[mt][nt][r] + bias[nt];
                float sp = fmaxf(v, 0.f) + log1pf(__expf(-fabsf(v)));
                out[((size_t)(b * 60 + t) * 400 + n) * 64 + u] = sp;
            }
        }
}

// ---------------------------------------------------------------------------
extern "C" void kernel_launch(void* const* d_in, const int* in_sizes, int n_in,
                              void* d_out, int out_size, void* d_ws, size_t ws_size,
                              hipStream_t stream)
{
    const float* x    = (const float*)d_in[0];
    const float* A    = (const float*)d_in[1];
    const float* W1   = (const float*)d_in[2];
    const float* W2   = (const float*)d_in[3];
    const float* W3   = (const float*)d_in[4];
    const float* b1   = (const float*)d_in[5];
    const float* b2   = (const float*)d_in[6];
    const float* taW1 = (const float*)d_in[7];
    const float* taW2 = (const float*)d_in[8];
    const float* taW3 = (const float*)d_in[9];
    const float* Ve   = (const float*)d_in[10];
    const float* be   = (const float*)d_in[11];
    const float* tk   = (const float*)d_in[12];
    const float* tb   = (const float*)d_in[13];
    const float* rk   = (const float*)d_in[14];
    const float* rb   = (const float*)d_in[15];
    float* out = (float*)d_out;

    char* wsb = (char*)d_ws;
    size_t off = 0;
    auto alloc = [&](size_t bytes) -> void* {
        void* p = wsb + off;
        off += (bytes + 255) & ~(size_t)255;
        return p;
    };
    short* AWF           = (short*)alloc((size_t)186368 * 2);
    short* W2F           = (short*)alloc((size_t)25600 * 2);
    short* W3F           = (short*)alloc((size_t)4096 * 2);
    unsigned char* Ab2   = (unsigned char*)alloc((size_t)448 * 448);
    short* xF            = (short*)alloc((size_t)480 * 26624 * 2);
    unsigned char* xF8   = (unsigned char*)alloc((size_t)480 * 26624);
    short* y             = (short*)alloc((size_t)480 * 400 * 64 * 2);
    float* r1            = (float*)alloc(480 * 64 * 4);
    float* rhs           = (float*)alloc(480 * 400 * 4);
    float* lhs           = (float*)alloc(480 * 400 * 4);
    float* Sbuf          = (float*)alloc(8 * 3600 * 4);
    float* ker           = (float*)alloc(8 * 3600 * 4);
    short* KTF           = (short*)alloc((size_t)98304 * 2);

    hipMemsetAsync(r1, 0, 480 * 64 * 4, stream);
    prep_w<<<890, 256, 0, stream>>>(A, W1, W2, W3, AWF, W2F, W3F, Ab2);
    prep_xt<<<6240, 256, 0, stream>>>(x, xF, xF8);
    dgc_mfma<<<13440, 64, 0, stream>>>(b1, b2, (const unsigned*)Ab2,
                                       AWF, W2F, W3F, xF, xF8,
                                       taW1, taW3, y, rhs, r1);
    ta_lhs<<<480, 256, 0, stream>>>(r1, taW2, lhs);
    ta_product<<<dim3(15, 8), 256, 0, stream>>>(lhs, rhs, be, Sbuf);
    ta_softmax<<<8, 256, 0, stream>>>(Sbuf, Ve, ker);
    ktf_prep<<<384, 256, 0, stream>>>(tk, rk, KTF);
    fused_conv<<<dim3(400, 8), 256, 0, stream>>>(y, ker, x, KTF, tb, rb, out);
}

// Round 5
// 441.276 us; speedup vs baseline: 1.0077x; 1.0077x over previous
//
#include <hip/hip_runtime.h>
#include <hip/hip_bf16.h>

typedef __attribute__((ext_vector_type(8))) short short8;   // 8 bf16 (4 VGPRs)
typedef __attribute__((ext_vector_type(4))) short short4_t; // 8 B
typedef __attribute__((ext_vector_type(4))) float f32x4;    // MFMA 16x16 acc

union S8u { short8 v; short4_t h[2]; };
union P8u { unsigned char b[8]; long v; };

static __device__ __forceinline__ short f2b(float f) {
    union { float f; unsigned u; } v; v.f = f;
    unsigned r = v.u + 0x7FFFu + ((v.u >> 16) & 1u);   // RNE
    return (short)(r >> 16);
}
static __device__ __forceinline__ unsigned char f2fp8(float f) {
    return (unsigned char)(__builtin_amdgcn_cvt_pk_fp8_f32(f, f, 0, false) & 0xff);
}

// ---------------------------------------------------------------------------
// prep_w: fragment buffers, one THREAD per (tile,lane) -> 8 elems.
//  tiles: [0,364) AWF  (g*13+kt):  A^T*W1^T [m=g*16+lm][n=kt*32+quad*8+j]
//         [364,414) W2F (jt*2+kh): W2[f=kh*32+quad*8+j][jc=jt*16+lm]
//         [414,422) W3F (ut*2+kh): W3[f][u=ut*16+lm]
//  then Ab2[448 m][448 j] bytes = (A[m][j] != 0), zero-padded (m,j >= 400).
// grid 890 x 256 (422*64 + 448*448 = 227712 threads)
// ---------------------------------------------------------------------------
__global__ __launch_bounds__(256) void prep_w(
    const float* __restrict__ A, const float* __restrict__ W1,
    const float* __restrict__ W2, const float* __restrict__ W3,
    short* __restrict__ AWF, short* __restrict__ W2F,
    short* __restrict__ W3F, unsigned char* __restrict__ Ab2)
{
    int t = blockIdx.x * 256 + threadIdx.x;
    if (t < 422 * 64) {
        int tile = t >> 6, lane = t & 63, lm = lane & 15, quad = lane >> 4;
        short8 o;
        if (tile < 364) {
            int kt = tile % 13, g = tile / 13;
            int m = g * 16 + lm;
#pragma unroll
            for (int j = 0; j < 8; ++j) {
                int n = kt * 32 + quad * 8 + j;
                float v = (m < 400 && n < 400) ? A[n * 400 + m] * W1[n * 400 + m] : 0.f;
                o[j] = f2b(v);
            }
            *(short8*)(AWF + tile * 512 + lane * 8) = o;
        } else if (tile < 414) {
            int t2 = tile - 364;
            int kh = t2 & 1, jt = t2 >> 1;
            int jc = jt * 16 + lm;
#pragma unroll
            for (int j = 0; j < 8; ++j) {
                int f = kh * 32 + quad * 8 + j;
                o[j] = f2b(W2[f * 400 + jc]);
            }
            *(short8*)(W2F + t2 * 512 + lane * 8) = o;
        } else {
            int t3 = tile - 414;
            int kh = t3 & 1, ut = t3 >> 1;
            int u = ut * 16 + lm;
#pragma unroll
            for (int j = 0; j < 8; ++j) {
                int f = kh * 32 + quad * 8 + j;
                o[j] = f2b(W3[f * 64 + u]);
            }
            *(short8*)(W3F + t3 * 512 + lane * 8) = o;
        }
    } else {
        int o = t - 27008;
        if (o < 448 * 448) {
            int m = o / 448, j = o - m * 448;
            Ab2[o] = (m < 400 && j < 400 && A[m * 400 + j] != 0.f) ? 1 : 0;
        }
    }
}

// ---------------------------------------------------------------------------
// prep_xt: xF / xF8 fragment-linear, no LDS. One wave per tile; thread
// gathers 8 elems via 8 wave-coalesced dword loads, writes 16B + 8B.
// grid 480*13 blocks; block = (bt, kt), 4 waves = ft 0..3.
// ---------------------------------------------------------------------------
__global__ __launch_bounds__(256) void prep_xt(
    const float* __restrict__ x, short* __restrict__ xF,
    unsigned char* __restrict__ xF8)
{
    int bt = blockIdx.x / 13, kt = blockIdx.x % 13;
    int tid = threadIdx.x, lane = tid & 63, ft = tid >> 6;
    int lm = lane & 15, quad = lane >> 4;
    const float* xs = x + (size_t)bt * 25600;
    int tile = kt * 4 + ft;
    int f = ft * 16 + lm;
    short8 ob; P8u p8;
#pragma unroll
    for (int j = 0; j < 8; ++j) {
        int n = kt * 32 + quad * 8 + j;
        float v = (n < 400) ? xs[(size_t)n * 64 + f] : 0.f;
        ob[j] = f2b(v);
        p8.b[j] = f2fp8(v);
    }
    size_t o = (size_t)bt * 26624 + tile * 512 + lane * 8;
    *(short8*)(xF + o) = ob;
    *(long*)(xF8 + o) = p8.v;
}

// ---------------------------------------------------------------------------
// dgc_mfma v8: v7 with the launch-bounds poison removed. v7's
// __launch_bounds__(64,4) squeezed the allocator to 64 VGPRs (< the ~95-float
// Phase B live set) -> scratch spills: FETCH 21->73 MB, WRITE 28->115 MB,
// dur 145->163 despite occupancy 29->40%. Bare __launch_bounds__(64) lifts
// the cap to 256; compiler allocates what it needs (~96-112), no scratch.
// Occupancy then LDS-bound: 9.7 KB/block -> 16 blocks/CU = 16 waves/CU
// (~50%), the TLP v7 was aiming for, spill-free.
// grid 13440 = 8 XCD * 60 bt * 28 row-groups (XCD-contiguous bt preserved).
// ---------------------------------------------------------------------------
__global__ __launch_bounds__(64) void dgc_mfma(
    const float* __restrict__ b1p, const float* __restrict__ b2p,
    const unsigned* __restrict__ Ab2,
    const short* __restrict__ AWF, const short* __restrict__ W2F,
    const short* __restrict__ W3F, const short* __restrict__ xF,
    const unsigned char* __restrict__ xF8,
    const float* __restrict__ taW1, const float* __restrict__ taW3,
    short* __restrict__ y, float* __restrict__ rhs, float* __restrict__ r1)
{
    int bid = blockIdx.x;
    int c = bid & 7, jj = bid >> 3;     // c = XCD (round-robin), jj in [0,1680)
    int bt = c * 60 + jj / 28;          // 60 consecutive bt per XCD
    int g  = jj % 28;                   // 16-row group: rows [g*16, g*16+16)
    int lane = threadIdx.x;
    int lm = lane & 15, quad = lane >> 4;

    __shared__ __align__(16) char  attnS8[16 * 440];
    __shared__ __align__(16) short featS[16 * 72];
    __shared__ __align__(16) float invS[16];

    {   // zero pad cols [400,440) of own strip
        *(long*)&attnS8[lm * 440 + 400 + quad * 8] = 0;
        if (quad == 0) *(long*)&attnS8[lm * 440 + 432] = 0;
    }

    const short* xtb = xF + (size_t)bt * 26624 + lane * 8;
    const unsigned char* xt8b = xF8 + (size_t)bt * 26624 + lane * 8;

    // ---- Phase A: feat stripe [16 x 64] = AWT @ x, batched 2 kt ----
    f32x4 fa[4];
#pragma unroll
    for (int i = 0; i < 4; ++i) fa[i] = (f32x4){0.f, 0.f, 0.f, 0.f};
    const short* awf = AWF + (size_t)g * 13 * 512 + lane * 8;
#pragma unroll
    for (int kb = 0; kb < 12; kb += 2) {
        short8 af0 = *(const short8*)(awf + kb * 512);
        short8 af1 = *(const short8*)(awf + (kb + 1) * 512);
        short8 bf[8];
#pragma unroll
        for (int ft = 0; ft < 4; ++ft) {
            bf[ft]     = *(const short8*)(xtb + (kb * 4 + ft) * 512);
            bf[4 + ft] = *(const short8*)(xtb + ((kb + 1) * 4 + ft) * 512);
        }
#pragma unroll
        for (int ft = 0; ft < 4; ++ft) {
            fa[ft] = __builtin_amdgcn_mfma_f32_16x16x32_bf16(af0, bf[ft], fa[ft], 0, 0, 0);
            fa[ft] = __builtin_amdgcn_mfma_f32_16x16x32_bf16(af1, bf[4 + ft], fa[ft], 0, 0, 0);
        }
    }
    {   // kt = 12 tail
        short8 af = *(const short8*)(awf + 12 * 512);
        short8 bf[4];
#pragma unroll
        for (int ft = 0; ft < 4; ++ft)
            bf[ft] = *(const short8*)(xtb + (48 + ft) * 512);
#pragma unroll
        for (int ft = 0; ft < 4; ++ft)
            fa[ft] = __builtin_amdgcn_mfma_f32_16x16x32_bf16(af, bf[ft], fa[ft], 0, 0, 0);
    }
#pragma unroll
    for (int ft = 0; ft < 4; ++ft)
#pragma unroll
        for (int r = 0; r < 4; ++r)
            featS[(quad * 4 + r) * 72 + ft * 16 + lm] = f2b(fa[ft][r]);

    // ---- Phase B (swapped): D' = W2^T @ feat^T, chunked 5 jt ----
    // Lane holds D'[j = jt*16+quad*4+r][m = g*16+lm] = dense[m][j].
    short8 a0 = *(const short8*)&featS[lm * 72 + quad * 8];
    short8 a1 = *(const short8*)&featS[lm * 72 + 32 + quad * 8];
    int m = g * 16 + lm;                             // lane's output row
    const unsigned* ab2 = Ab2 + (size_t)m * 112;     // Ab2[m][j] dwords
    float s_row = 0.f;
#pragma unroll
    for (int jb = 0; jb < 25; jb += 5) {
        short8 bf[10];
#pragma unroll
        for (int q = 0; q < 5; ++q) {
            bf[2 * q]     = *(const short8*)(W2F + ((jb + q) * 2 + 0) * 512 + lane * 8);
            bf[2 * q + 1] = *(const short8*)(W2F + ((jb + q) * 2 + 1) * 512 + lane * 8);
        }
        f32x4 da5[5];
#pragma unroll
        for (int q = 0; q < 5; ++q) {
            da5[q] = (f32x4){0.f, 0.f, 0.f, 0.f};
            da5[q] = __builtin_amdgcn_mfma_f32_16x16x32_bf16(bf[2 * q],     a0, da5[q], 0, 0, 0);
            da5[q] = __builtin_amdgcn_mfma_f32_16x16x32_bf16(bf[2 * q + 1], a1, da5[q], 0, 0, 0);
        }
#pragma unroll
        for (int q = 0; q < 5; ++q) {
            int jt = jb + q;
            float4 b1v = *(const float4*)(b1p + jt * 16 + quad * 4);
            unsigned mv = ab2[jt * 4 + quad];
            float e0 = (mv & 255u)         ? __expf(da5[q][0] + b1v.x) : 0.f;
            float e1 = ((mv >> 8) & 255u)  ? __expf(da5[q][1] + b1v.y) : 0.f;
            float e2 = ((mv >> 16) & 255u) ? __expf(da5[q][2] + b1v.z) : 0.f;
            float e3 = ((mv >> 24) & 255u) ? __expf(da5[q][3] + b1v.w) : 0.f;
            s_row += (e0 + e1) + (e2 + e3);
            int pk = __builtin_amdgcn_cvt_pk_fp8_f32(e0, e1, 0, false);
            pk = __builtin_amdgcn_cvt_pk_fp8_f32(e2, e3, pk, true);
            *(int*)&attnS8[lm * 440 + jt * 16 + quad * 4] = pk;
        }
    }
    s_row += __shfl_xor(s_row, 16);
    s_row += __shfl_xor(s_row, 32);
    float invv = (s_row > 0.f) ? (1.f / s_row) : 0.f;
    if (quad == 0) invS[lm] = invv;

    // ---- Phase D: nodef stripe [16 x 64] = attn_unnorm @ x (fp8) ----
    f32x4 na[4];
#pragma unroll
    for (int i = 0; i < 4; ++i) na[i] = (f32x4){0.f, 0.f, 0.f, 0.f};
    const char* at_row = attnS8 + lm * 440 + quad * 8;
#pragma unroll
    for (int kb = 0; kb < 12; kb += 2) {
        long af0 = *(const long*)(at_row + kb * 32);
        long af1 = *(const long*)(at_row + (kb + 1) * 32);
        long bf[8];
#pragma unroll
        for (int ft = 0; ft < 4; ++ft) {
            bf[ft]     = *(const long*)(xt8b + (kb * 4 + ft) * 512);
            bf[4 + ft] = *(const long*)(xt8b + ((kb + 1) * 4 + ft) * 512);
        }
#pragma unroll
        for (int ft = 0; ft < 4; ++ft) {
            na[ft] = __builtin_amdgcn_mfma_f32_16x16x32_fp8_fp8(af0, bf[ft], na[ft], 0, 0, 0);
            na[ft] = __builtin_amdgcn_mfma_f32_16x16x32_fp8_fp8(af1, bf[4 + ft], na[ft], 0, 0, 0);
        }
    }
    {   // kt = 12 tail
        long af = *(const long*)(at_row + 12 * 32);
        long bf[4];
#pragma unroll
        for (int ft = 0; ft < 4; ++ft)
            bf[ft] = *(const long*)(xt8b + (48 + ft) * 512);
#pragma unroll
        for (int ft = 0; ft < 4; ++ft)
            na[ft] = __builtin_amdgcn_mfma_f32_16x16x32_fp8_fp8(af, bf[ft], na[ft], 0, 0, 0);
    }
#pragma unroll
    for (int ft = 0; ft < 4; ++ft)
#pragma unroll
        for (int r = 0; r < 4; ++r)
            featS[(quad * 4 + r) * 72 + ft * 16 + lm] = f2b(na[ft][r]);

    // ---- Phase E: y stripe [16 x 64] = nodef @ W3, then * inv_s + b2 ----
    f32x4 ya[4];
#pragma unroll
    for (int i = 0; i < 4; ++i) ya[i] = (f32x4){0.f, 0.f, 0.f, 0.f};
    short8 nf0 = *(const short8*)&featS[lm * 72 + quad * 8];
    short8 nf1 = *(const short8*)&featS[lm * 72 + 32 + quad * 8];
    {
        short8 wb[8];
#pragma unroll
        for (int ut = 0; ut < 4; ++ut) {
            wb[2 * ut]     = *(const short8*)(W3F + (ut * 2 + 0) * 512 + lane * 8);
            wb[2 * ut + 1] = *(const short8*)(W3F + (ut * 2 + 1) * 512 + lane * 8);
        }
#pragma unroll
        for (int ut = 0; ut < 4; ++ut) {
            ya[ut] = __builtin_amdgcn_mfma_f32_16x16x32_bf16(nf0, wb[2 * ut], ya[ut], 0, 0, 0);
            ya[ut] = __builtin_amdgcn_mfma_f32_16x16x32_bf16(nf1, wb[2 * ut + 1], ya[ut], 0, 0, 0);
        }
    }

    // ---- Epilogue: deferred softmax scale, y store + rhs + r1 partials ----
    int mrb = g * 16 + quad * 4;                    // 4-aligned
    float4 inv4 = *(const float4*)&invS[quad * 4];  // rows mrb..mrb+3
    float invr[4] = {inv4.x, inv4.y, inv4.z, inv4.w};
    float yv[4][4];
#pragma unroll
    for (int ut = 0; ut < 4; ++ut) {
        int u = ut * 16 + lm;
        float b2v = b2p[u];
#pragma unroll
        for (int r = 0; r < 4; ++r) {
            yv[ut][r] = ya[ut][r] * invr[r] + b2v;
            int mrow = mrb + r;
            if (mrow < 400)
                y[((size_t)bt * 400 + mrow) * 64 + u] = f2b(yv[ut][r]);
        }
    }
    // rhs[bt, mrb+r] = sum_u yv*taW3[u] (reduce over 16 lanes of quad)
    float w3r[4];
#pragma unroll
    for (int ut = 0; ut < 4; ++ut) w3r[ut] = taW3[ut * 16 + lm];
    float rv[4];
#pragma unroll
    for (int r = 0; r < 4; ++r) {
        float v = yv[0][r] * w3r[0] + yv[1][r] * w3r[1] +
                  yv[2][r] * w3r[2] + yv[3][r] * w3r[3];
        v += __shfl_xor(v, 1);
        v += __shfl_xor(v, 2);
        v += __shfl_xor(v, 4);
        v += __shfl_xor(v, 8);
        rv[r] = v;
    }
    if (lm == 0 && mrb < 400)
        *(float4*)(rhs + (size_t)bt * 400 + mrb) = make_float4(rv[0], rv[1], rv[2], rv[3]);
    // r1[bt, u] += sum_rows yv*taW1[row] (reduce over quads, atomic)
    float p[4] = {0.f, 0.f, 0.f, 0.f};
#pragma unroll
    for (int r = 0; r < 4; ++r) {
        int mrow = mrb + r;
        if (mrow < 400) {
            float w1v = taW1[mrow];
#pragma unroll
            for (int ut = 0; ut < 4; ++ut) p[ut] += yv[ut][r] * w1v;
        }
    }
#pragma unroll
    for (int ut = 0; ut < 4; ++ut) {
        p[ut] += __shfl_xor(p[ut], 16);
        p[ut] += __shfl_xor(p[ut], 32);
    }
    if (quad == 0) {
#pragma unroll
        for (int ut = 0; ut < 4; ++ut)
            atomicAdd(&r1[bt * 64 + ut * 16 + lm], p[ut]);
    }
}

// ---------------------------------------------------------------------------
// ta_lhs: lhs[bt,n] = sum_f r1[bt,f] * taW2[f,n]
// ---------------------------------------------------------------------------
__global__ __launch_bounds__(256) void ta_lhs(
    const float* __restrict__ r1, const float* __restrict__ taW2,
    float* __restrict__ lhs)
{
    int bt = blockIdx.x, tid = threadIdx.x;
    __shared__ float r1s[64];
    if (tid < 64) r1s[tid] = r1[bt * 64 + tid];
    __syncthreads();
    for (int n = tid; n < 400; n += 256) {
        float acc = 0.f;
#pragma unroll 8
        for (int f = 0; f < 64; ++f) acc += r1s[f] * taW2[f * 400 + n];
        lhs[bt * 400 + n] = acc;
    }
}

// ---------------------------------------------------------------------------
// ta_product: S[b,k,l] = sigmoid( lhs[b,k,:].rhs[b,l,:] + be[k,l] )
// ---------------------------------------------------------------------------
__global__ __launch_bounds__(256) void ta_product(
    const float* __restrict__ lhs, const float* __restrict__ rhs,
    const float* __restrict__ be, float* __restrict__ S)
{
    int kc = blockIdx.x, b = blockIdx.y, tid = threadIdx.x;
    if (tid >= 240) return;
    int k = kc * 4 + tid / 60;
    int l = tid % 60;
    const float4* lr = (const float4*)(lhs + (size_t)(b * 60 + k) * 400);
    const float4* rr = (const float4*)(rhs + (size_t)(b * 60 + l) * 400);
    float acc = 0.f;
    for (int q = 0; q < 100; ++q) {
        float4 a = lr[q], c = rr[q];
        acc += a.x * c.x + a.y * c.y + a.z * c.z + a.w * c.w;
    }
    float v = acc + be[k * 60 + l];
    S[b * 3600 + k * 60 + l] = 1.f / (1.f + __expf(-v));
}

// ---------------------------------------------------------------------------
// ta_softmax: E[b,j,l] = sum_k Ve[j,k]*S[b,k,l]; ker = softmax over j.
// ---------------------------------------------------------------------------
__global__ __launch_bounds__(256) void ta_softmax(
    const float* __restrict__ S, const float* __restrict__ Ve,
    float* __restrict__ ker)
{
    int b = blockIdx.x, tid = threadIdx.x;
    __shared__ float Ss[3600];
    __shared__ float Emat[3600];
    for (int i = tid; i < 3600; i += 256) Ss[i] = S[b * 3600 + i];
    __syncthreads();
    for (int p = tid; p < 3600; p += 256) {
        int j = p / 60, l = p % 60;
        float acc = 0.f;
        for (int k = 0; k < 60; ++k) acc += Ve[j * 60 + k] * Ss[k * 60 + l];
        Emat[p] = acc;
    }
    __syncthreads();
    for (int l = tid; l < 60; l += 256) {
        float mx = -1e30f;
        for (int j = 0; j < 60; ++j) mx = fmaxf(mx, Emat[j * 60 + l]);
        float s = 0.f;
        for (int j = 0; j < 60; ++j) s += __expf(Emat[j * 60 + l] - mx);
        float inv = 1.f / s;
        for (int j = 0; j < 60; ++j)
            ker[b * 3600 + j * 60 + l] = __expf(Emat[j * 60 + l] - mx) * inv;
    }
}

// ---------------------------------------------------------------------------
// ktf_prep: fragment-linear conv weights (unchanged).
// ---------------------------------------------------------------------------
__global__ __launch_bounds__(256) void ktf_prep(
    const float* __restrict__ tk, const float* __restrict__ rk,
    short* __restrict__ KTF)
{
    int i = blockIdx.x * 256 + threadIdx.x;      // [0, 98304)
    int j = i & 7, lane = (i >> 3) & 63, tile = i >> 9;   // tile in [0,192)
    int kkt = tile % 48, ng = tile / 48;
    int u = (ng >> 1) * 32 + (ng & 1) * 16 + (lane & 15);
    int kk = kkt * 32 + (lane >> 4) * 8 + j;
    int dt = kk >> 7, c = kk & 127;
    float v = (c < 64) ? tk[dt * 4096 + c * 64 + u]
                       : rk[dt * 4096 + (c - 64) * 64 + u];
    KTF[i] = f2b(v);
}

// ---------------------------------------------------------------------------
// fused_conv: time-mix + both temporal convs + softplus, bf16 MFMA.
// Conv K-loop batched 2 kkt for load overlap.
// ---------------------------------------------------------------------------
#define IN_S 132
__global__ __launch_bounds__(256, 4) void fused_conv(
    const short* __restrict__ y, const float* __restrict__ ker,
    const float* __restrict__ x, const short* __restrict__ KTF,
    const float* __restrict__ tb, const float* __restrict__ rb,
    float* __restrict__ out)
{
    int n = blockIdx.x, b = blockIdx.y;
    int tid = threadIdx.x, lane = tid & 63, w = tid >> 6;
    int m = lane & 15, quad = lane >> 4;
    int hm = w >> 1, hn = w & 1;

    __shared__ __align__(16) short In[75 * IN_S];
    __shared__ __align__(16) short kerT[64 * 72];
    __shared__ __align__(16) short ybT[64 * 72];

    for (int i = tid; i < 75 * IN_S; i += 256) In[i] = 0;
    for (int i = tid; i < 64 * 72; i += 256) { kerT[i] = 0; ybT[i] = 0; }
    __syncthreads();

    for (int i = tid; i < 3840; i += 256) {
        int t = i >> 6, u = i & 63;
        In[(t + 5) * IN_S + 64 + u] = f2b(x[((size_t)(b * 60 + t) * 400 + n) * 64 + u]);
    }
    for (int i = tid; i < 3840; i += 256) {
        int s = i >> 6, u = i & 63;
        ybT[u * 72 + s] = y[((size_t)(b * 60 + s) * 400 + n) * 64 + u];
    }
    for (int i = tid; i < 3600; i += 256) {
        int s = i / 60, t = i - s * 60;
        kerT[t * 72 + s] = f2b(ker[b * 3600 + s * 60 + t]);
    }
    __syncthreads();

    // ---- time-mix GEMM (M=64,N=64,K=64) ----
    f32x4 tacc[2][2];
#pragma unroll
    for (int a = 0; a < 2; ++a)
#pragma unroll
        for (int c = 0; c < 2; ++c) tacc[a][c] = (f32x4){0.f, 0.f, 0.f, 0.f};
#pragma unroll
    for (int k0 = 0; k0 < 64; k0 += 32) {
        short8 afr[2], bfr[2];
#pragma unroll
        for (int mt = 0; mt < 2; ++mt)
            afr[mt] = *(const short8*)&kerT[(hm * 32 + mt * 16 + m) * 72 + k0 + quad * 8];
#pragma unroll
        for (int nt = 0; nt < 2; ++nt)
            bfr[nt] = *(const short8*)&ybT[(hn * 32 + nt * 16 + m) * 72 + k0 + quad * 8];
#pragma unroll
        for (int mt = 0; mt < 2; ++mt)
#pragma unroll
            for (int nt = 0; nt < 2; ++nt)
                tacc[mt][nt] = __builtin_amdgcn_mfma_f32_16x16x32_bf16(
                    afr[mt], bfr[nt], tacc[mt][nt], 0, 0, 0);
    }
    __syncthreads();

#pragma unroll
    for (int mt = 0; mt < 2; ++mt)
#pragma unroll
        for (int nt = 0; nt < 2; ++nt)
#pragma unroll
            for (int r = 0; r < 4; ++r) {
                int t = hm * 32 + mt * 16 + quad * 4 + r;
                int u = hn * 32 + nt * 16 + m;
                if (t < 60) In[(t + 5) * IN_S + u] = f2b(tacc[mt][nt][r]);
            }
    __syncthreads();

    // ---- conv GEMM (M=64,N=64,K=1536), batched 2 kkt ----
    f32x4 acc[2][2];
#pragma unroll
    for (int a = 0; a < 2; ++a)
#pragma unroll
        for (int c = 0; c < 2; ++c) acc[a][c] = (f32x4){0.f, 0.f, 0.f, 0.f};

    const short* ktf0 = KTF + (size_t)(hn * 2 + 0) * 48 * 512 + lane * 8;
    const short* ktf1 = KTF + (size_t)(hn * 2 + 1) * 48 * 512 + lane * 8;

#pragma unroll 4
    for (int kb = 0; kb < 48; kb += 2) {
        S8u a0[2], a1[2];
        short8 b0[2], b1[2];
#pragma unroll
        for (int q = 0; q < 2; ++q) {
            int kk = (kb + q) * 32;
            int dt = kk >> 7, c0 = (kk & 127) + quad * 8;
            int i0 = (hm * 32 + m + dt) * IN_S + c0;
            int i1 = i0 + 16 * IN_S;
            a0[q].h[0] = *(const short4_t*)&In[i0];
            a0[q].h[1] = *(const short4_t*)&In[i0 + 4];
            a1[q].h[0] = *(const short4_t*)&In[i1];
            a1[q].h[1] = *(const short4_t*)&In[i1 + 4];
            b0[q] = *(const short8*)(ktf0 + (kb + q) * 512);
            b1[q] = *(const short8*)(ktf1 + (kb + q) * 512);
        }
#pragma unroll
        for (int q = 0; q < 2; ++q) {
            acc[0][0] = __builtin_amdgcn_mfma_f32_16x16x32_bf16(a0[q].v, b0[q], acc[0][0], 0, 0, 0);
            acc[0][1] = __builtin_amdgcn_mfma_f32_16x16x32_bf16(a0[q].v, b1[q], acc[0][1], 0, 0, 0);
            acc[1][0] = __builtin_amdgcn_mfma_f32_16x16x32_bf16(a1[q].v, b0[q], acc[1][0], 0, 0, 0);
            acc[1][1] = __builtin_amdgcn_mfma_f32_16x16x32_bf16(a1[q].v, b1[q], acc[1][1], 0, 0, 0);
        }
    }

    float bias[2];
#pragma unroll
    for (int nt = 0; nt < 2; ++nt) {
        int u = hn * 32 + nt * 16 + m;
        bias[nt] = tb[u] + rb[u];
    }
#pragma unroll
    for (int mt = 0; mt < 2; ++mt)
#pragma unroll
        for (int r = 0; r < 4; ++r) {
            int t = hm * 32 + mt * 16 + quad * 4 + r;
            if (t >= 60) continue;
#pragma unroll
            for (int nt = 0; nt < 2; ++nt) {
                int u = hn * 32 + nt * 16 + m;
                float v = acc[mt][nt][r] + bias[nt];
                float sp = fmaxf(v, 0.f) + log1pf(__expf(-fabsf(v)));
                out[((size_t)(b * 60 + t) * 400 + n) * 64 + u] = sp;
            }
        }
}

// ---------------------------------------------------------------------------
extern "C" void kernel_launch(void* const* d_in, const int* in_sizes, int n_in,
                              void* d_out, int out_size, void* d_ws, size_t ws_size,
                              hipStream_t stream)
{
    const float* x    = (const float*)d_in[0];
    const float* A    = (const float*)d_in[1];
    const float* W1   = (const float*)d_in[2];
    const float* W2   = (const float*)d_in[3];
    const float* W3   = (const float*)d_in[4];
    const float* b1   = (const float*)d_in[5];
    const float* b2   = (const float*)d_in[6];
    const float* taW1 = (const float*)d_in[7];
    const float* taW2 = (const float*)d_in[8];
    const float* taW3 = (const float*)d_in[9];
    const float* Ve   = (const float*)d_in[10];
    const float* be   = (const float*)d_in[11];
    const float* tk   = (const float*)d_in[12];
    const float* tb   = (const float*)d_in[13];
    const float* rk   = (const float*)d_in[14];
    const float* rb   = (const float*)d_in[15];
    float* out = (float*)d_out;

    char* wsb = (char*)d_ws;
    size_t off = 0;
    auto alloc = [&](size_t bytes) -> void* {
        void* p = wsb + off;
        off += (bytes + 255) & ~(size_t)255;
        return p;
    };
    short* AWF           = (short*)alloc((size_t)186368 * 2);
    short* W2F           = (short*)alloc((size_t)25600 * 2);
    short* W3F           = (short*)alloc((size_t)4096 * 2);
    unsigned char* Ab2   = (unsigned char*)alloc((size_t)448 * 448);
    short* xF            = (short*)alloc((size_t)480 * 26624 * 2);
    unsigned char* xF8   = (unsigned char*)alloc((size_t)480 * 26624);
    short* y             = (short*)alloc((size_t)480 * 400 * 64 * 2);
    float* r1            = (float*)alloc(480 * 64 * 4);
    float* rhs           = (float*)alloc(480 * 400 * 4);
    float* lhs           = (float*)alloc(480 * 400 * 4);
    float* Sbuf          = (float*)alloc(8 * 3600 * 4);
    float* ker           = (float*)alloc(8 * 3600 * 4);
    short* KTF           = (short*)alloc((size_t)98304 * 2);

    hipMemsetAsync(r1, 0, 480 * 64 * 4, stream);
    prep_w<<<890, 256, 0, stream>>>(A, W1, W2, W3, AWF, W2F, W3F, Ab2);
    prep_xt<<<6240, 256, 0, stream>>>(x, xF, xF8);
    dgc_mfma<<<13440, 64, 0, stream>>>(b1, b2, (const unsigned*)Ab2,
                                       AWF, W2F, W3F, xF, xF8,
                                       taW1, taW3, y, rhs, r1);
    ta_lhs<<<480, 256, 0, stream>>>(r1, taW2, lhs);
    ta_product<<<dim3(15, 8), 256, 0, stream>>>(lhs, rhs, be, Sbuf);
    ta_softmax<<<8, 256, 0, stream>>>(Sbuf, Ve, ker);
    ktf_prep<<<384, 256, 0, stream>>>(tk, rk, KTF);
    fused_conv<<<dim3(400, 8), 256, 0, stream>>>(y, ker, x, KTF, tb, rb, out);
}

// Round 6
// 390.831 us; speedup vs baseline: 1.1378x; 1.1291x over previous
//
#include <hip/hip_runtime.h>
#include <hip/hip_bf16.h>

typedef __attribute__((ext_vector_type(8))) short short8;   // 8 bf16 (4 VGPRs)
typedef __attribute__((ext_vector_type(4))) short short4_t; // 8 B
typedef __attribute__((ext_vector_type(4))) float f32x4;    // MFMA 16x16 acc

union S8u { short8 v; short4_t h[2]; };
union P8u { unsigned char b[8]; long v; };

static __device__ __forceinline__ short f2b(float f) {
    union { float f; unsigned u; } v; v.f = f;
    unsigned r = v.u + 0x7FFFu + ((v.u >> 16) & 1u);   // RNE
    return (short)(r >> 16);
}
static __device__ __forceinline__ unsigned char f2fp8(float f) {
    return (unsigned char)(__builtin_amdgcn_cvt_pk_fp8_f32(f, f, 0, false) & 0xff);
}

// ---------------------------------------------------------------------------
// prep_w: fragment buffers, one THREAD per (tile,lane) -> 8 elems.
//  tiles: [0,364) AWF  (g*13+kt):  A^T*W1^T [m=g*16+lm][n=kt*32+quad*8+j]
//         [364,414) W2F (jt*2+kh): W2[f=kh*32+quad*8+j][jc=jt*16+lm]
//         [414,422) W3F (ut*2+kh): W3[f][u=ut*16+lm]
//  then Ab2[448 m][448 j] bytes = (A[m][j] != 0), zero-padded (m,j >= 400).
// grid 890 x 256 (422*64 + 448*448 = 227712 threads)
// ---------------------------------------------------------------------------
__global__ __launch_bounds__(256) void prep_w(
    const float* __restrict__ A, const float* __restrict__ W1,
    const float* __restrict__ W2, const float* __restrict__ W3,
    short* __restrict__ AWF, short* __restrict__ W2F,
    short* __restrict__ W3F, unsigned char* __restrict__ Ab2)
{
    int t = blockIdx.x * 256 + threadIdx.x;
    if (t < 422 * 64) {
        int tile = t >> 6, lane = t & 63, lm = lane & 15, quad = lane >> 4;
        short8 o;
        if (tile < 364) {
            int kt = tile % 13, g = tile / 13;
            int m = g * 16 + lm;
#pragma unroll
            for (int j = 0; j < 8; ++j) {
                int n = kt * 32 + quad * 8 + j;
                float v = (m < 400 && n < 400) ? A[n * 400 + m] * W1[n * 400 + m] : 0.f;
                o[j] = f2b(v);
            }
            *(short8*)(AWF + tile * 512 + lane * 8) = o;
        } else if (tile < 414) {
            int t2 = tile - 364;
            int kh = t2 & 1, jt = t2 >> 1;
            int jc = jt * 16 + lm;
#pragma unroll
            for (int j = 0; j < 8; ++j) {
                int f = kh * 32 + quad * 8 + j;
                o[j] = f2b(W2[f * 400 + jc]);
            }
            *(short8*)(W2F + t2 * 512 + lane * 8) = o;
        } else {
            int t3 = tile - 414;
            int kh = t3 & 1, ut = t3 >> 1;
            int u = ut * 16 + lm;
#pragma unroll
            for (int j = 0; j < 8; ++j) {
                int f = kh * 32 + quad * 8 + j;
                o[j] = f2b(W3[f * 64 + u]);
            }
            *(short8*)(W3F + t3 * 512 + lane * 8) = o;
        }
    } else {
        int o = t - 27008;
        if (o < 448 * 448) {
            int m = o / 448, j = o - m * 448;
            Ab2[o] = (m < 400 && j < 400 && A[m * 400 + j] != 0.f) ? 1 : 0;
        }
    }
}

// ---------------------------------------------------------------------------
// prep_xt: xF / xF8 fragment-linear, no LDS. One wave per tile; thread
// gathers 8 elems via 8 wave-coalesced dword loads, writes 16B + 8B.
// grid 480*13 blocks; block = (bt, kt), 4 waves = ft 0..3.
// ---------------------------------------------------------------------------
__global__ __launch_bounds__(256) void prep_xt(
    const float* __restrict__ x, short* __restrict__ xF,
    unsigned char* __restrict__ xF8)
{
    int bt = blockIdx.x / 13, kt = blockIdx.x % 13;
    int tid = threadIdx.x, lane = tid & 63, ft = tid >> 6;
    int lm = lane & 15, quad = lane >> 4;
    const float* xs = x + (size_t)bt * 25600;
    int tile = kt * 4 + ft;
    int f = ft * 16 + lm;
    short8 ob; P8u p8;
#pragma unroll
    for (int j = 0; j < 8; ++j) {
        int n = kt * 32 + quad * 8 + j;
        float v = (n < 400) ? xs[(size_t)n * 64 + f] : 0.f;
        ob[j] = f2b(v);
        p8.b[j] = f2fp8(v);
    }
    size_t o = (size_t)bt * 26624 + tile * 512 + lane * 8;
    *(short8*)(xF + o) = ob;
    *(long*)(xF8 + o) = p8.v;
}

// ---------------------------------------------------------------------------
// dgc_mfma v9: 2 ROW-GROUPS PER WAVE. Evidence from v6/v7/v8: dur pinned at
// 145-160us across occupancy 6.6-12.7 waves/CU -> not TLP-bound. Per-wave L2
// reads ~149KB x 13440 waves = 2.0GB -> ~13-14 TB/s sustained = L2-BW-bound.
// Fix: one wave handles rows [gg*32, gg*32+32) (two 16-row groups), sharing
// the xF/xF8/W2F/W3F reads between them: per-wave 162KB for 2 groups
// (was 2x149KB) -> total L2 read 1.09GB (/1.84). No barriers, wave-private
// LDS strips, bare launch_bounds(64) (R3 lesson: min-waves attr => spills).
// grid 6720 = 8 XCD * 60 bt * 14 group-pairs (XCD-contiguous bt preserved).
// ---------------------------------------------------------------------------
__global__ __launch_bounds__(64) void dgc_mfma(
    const float* __restrict__ b1p, const float* __restrict__ b2p,
    const unsigned* __restrict__ Ab2,
    const short* __restrict__ AWF, const short* __restrict__ W2F,
    const short* __restrict__ W3F, const short* __restrict__ xF,
    const unsigned char* __restrict__ xF8,
    const float* __restrict__ taW1, const float* __restrict__ taW3,
    short* __restrict__ y, float* __restrict__ rhs, float* __restrict__ r1)
{
    int bid = blockIdx.x;
    int c = bid & 7, jj = bid >> 3;     // c = XCD (round-robin), jj in [0,840)
    int bt = c * 60 + jj / 14;          // 60 consecutive bt per XCD
    int gg = jj % 14;                   // pair of 16-row groups: g0=2gg, g1=2gg+1
    int g0 = gg * 2;
    int lane = threadIdx.x;
    int lm = lane & 15, quad = lane >> 4;

    __shared__ __align__(16) char  attnS8[32 * 440];
    __shared__ __align__(16) short featS[32 * 72];
    __shared__ __align__(16) float invS[32];

    {   // zero pad cols [400,440) of both strips (rows lm and 16+lm)
        *(long*)&attnS8[lm * 440 + 400 + quad * 8] = 0;
        *(long*)&attnS8[(16 + lm) * 440 + 400 + quad * 8] = 0;
        if (quad == 0) {
            *(long*)&attnS8[lm * 440 + 432] = 0;
            *(long*)&attnS8[(16 + lm) * 440 + 432] = 0;
        }
    }

    const short* xtb = xF + (size_t)bt * 26624 + lane * 8;
    const unsigned char* xt8b = xF8 + (size_t)bt * 26624 + lane * 8;

    // ---- Phase A: feat [32 x 64] = AWT @ x, 2 groups share the bf loads ----
    f32x4 fa[2][4];
#pragma unroll
    for (int grp = 0; grp < 2; ++grp)
#pragma unroll
        for (int i = 0; i < 4; ++i) fa[grp][i] = (f32x4){0.f, 0.f, 0.f, 0.f};
    const short* awf0 = AWF + (size_t)g0 * 13 * 512 + lane * 8;
    const short* awf1 = awf0 + 13 * 512;
#pragma unroll
    for (int kb = 0; kb < 12; kb += 2) {
        short8 a00 = *(const short8*)(awf0 + kb * 512);
        short8 a01 = *(const short8*)(awf0 + (kb + 1) * 512);
        short8 a10 = *(const short8*)(awf1 + kb * 512);
        short8 a11 = *(const short8*)(awf1 + (kb + 1) * 512);
        short8 bf[8];
#pragma unroll
        for (int ft = 0; ft < 4; ++ft) {
            bf[ft]     = *(const short8*)(xtb + (kb * 4 + ft) * 512);
            bf[4 + ft] = *(const short8*)(xtb + ((kb + 1) * 4 + ft) * 512);
        }
#pragma unroll
        for (int ft = 0; ft < 4; ++ft) {
            fa[0][ft] = __builtin_amdgcn_mfma_f32_16x16x32_bf16(a00, bf[ft],     fa[0][ft], 0, 0, 0);
            fa[0][ft] = __builtin_amdgcn_mfma_f32_16x16x32_bf16(a01, bf[4 + ft], fa[0][ft], 0, 0, 0);
            fa[1][ft] = __builtin_amdgcn_mfma_f32_16x16x32_bf16(a10, bf[ft],     fa[1][ft], 0, 0, 0);
            fa[1][ft] = __builtin_amdgcn_mfma_f32_16x16x32_bf16(a11, bf[4 + ft], fa[1][ft], 0, 0, 0);
        }
    }
    {   // kt = 12 tail
        short8 a0t = *(const short8*)(awf0 + 12 * 512);
        short8 a1t = *(const short8*)(awf1 + 12 * 512);
        short8 bf[4];
#pragma unroll
        for (int ft = 0; ft < 4; ++ft)
            bf[ft] = *(const short8*)(xtb + (48 + ft) * 512);
#pragma unroll
        for (int ft = 0; ft < 4; ++ft) {
            fa[0][ft] = __builtin_amdgcn_mfma_f32_16x16x32_bf16(a0t, bf[ft], fa[0][ft], 0, 0, 0);
            fa[1][ft] = __builtin_amdgcn_mfma_f32_16x16x32_bf16(a1t, bf[ft], fa[1][ft], 0, 0, 0);
        }
    }
#pragma unroll
    for (int grp = 0; grp < 2; ++grp)
#pragma unroll
        for (int ft = 0; ft < 4; ++ft)
#pragma unroll
            for (int r = 0; r < 4; ++r)
                featS[(grp * 16 + quad * 4 + r) * 72 + ft * 16 + lm] = f2b(fa[grp][ft][r]);

    // ---- Phase B (swapped): D' = W2^T @ feat^T, chunked 5 jt, 2 groups ----
    // Lane holds D'[j = jt*16+quad*4+r][m = (g0+grp)*16+lm] = dense[m][j].
    short8 a0g0 = *(const short8*)&featS[lm * 72 + quad * 8];
    short8 a1g0 = *(const short8*)&featS[lm * 72 + 32 + quad * 8];
    short8 a0g1 = *(const short8*)&featS[(16 + lm) * 72 + quad * 8];
    short8 a1g1 = *(const short8*)&featS[(16 + lm) * 72 + 32 + quad * 8];
    int m0 = g0 * 16 + lm;                            // group-0 output row
    const unsigned* ab20 = Ab2 + (size_t)m0 * 112;    // Ab2[m][j] dwords
    const unsigned* ab21 = ab20 + 16 * 112;
    float s0 = 0.f, s1 = 0.f;
#pragma unroll
    for (int jb = 0; jb < 25; jb += 5) {
        short8 bf[10];
#pragma unroll
        for (int q = 0; q < 5; ++q) {
            bf[2 * q]     = *(const short8*)(W2F + ((jb + q) * 2 + 0) * 512 + lane * 8);
            bf[2 * q + 1] = *(const short8*)(W2F + ((jb + q) * 2 + 1) * 512 + lane * 8);
        }
        f32x4 d0[5], d1[5];
#pragma unroll
        for (int q = 0; q < 5; ++q) {
            d0[q] = (f32x4){0.f, 0.f, 0.f, 0.f};
            d0[q] = __builtin_amdgcn_mfma_f32_16x16x32_bf16(bf[2 * q],     a0g0, d0[q], 0, 0, 0);
            d0[q] = __builtin_amdgcn_mfma_f32_16x16x32_bf16(bf[2 * q + 1], a1g0, d0[q], 0, 0, 0);
            d1[q] = (f32x4){0.f, 0.f, 0.f, 0.f};
            d1[q] = __builtin_amdgcn_mfma_f32_16x16x32_bf16(bf[2 * q],     a0g1, d1[q], 0, 0, 0);
            d1[q] = __builtin_amdgcn_mfma_f32_16x16x32_bf16(bf[2 * q + 1], a1g1, d1[q], 0, 0, 0);
        }
#pragma unroll
        for (int q = 0; q < 5; ++q) {
            int jt = jb + q;
            float4 b1v = *(const float4*)(b1p + jt * 16 + quad * 4);
            {
                unsigned mv = ab20[jt * 4 + quad];
                float e0 = (mv & 255u)         ? __expf(d0[q][0] + b1v.x) : 0.f;
                float e1 = ((mv >> 8) & 255u)  ? __expf(d0[q][1] + b1v.y) : 0.f;
                float e2 = ((mv >> 16) & 255u) ? __expf(d0[q][2] + b1v.z) : 0.f;
                float e3 = ((mv >> 24) & 255u) ? __expf(d0[q][3] + b1v.w) : 0.f;
                s0 += (e0 + e1) + (e2 + e3);
                int pk = __builtin_amdgcn_cvt_pk_fp8_f32(e0, e1, 0, false);
                pk = __builtin_amdgcn_cvt_pk_fp8_f32(e2, e3, pk, true);
                *(int*)&attnS8[lm * 440 + jt * 16 + quad * 4] = pk;
            }
            {
                unsigned mv = ab21[jt * 4 + quad];
                float e0 = (mv & 255u)         ? __expf(d1[q][0] + b1v.x) : 0.f;
                float e1 = ((mv >> 8) & 255u)  ? __expf(d1[q][1] + b1v.y) : 0.f;
                float e2 = ((mv >> 16) & 255u) ? __expf(d1[q][2] + b1v.z) : 0.f;
                float e3 = ((mv >> 24) & 255u) ? __expf(d1[q][3] + b1v.w) : 0.f;
                s1 += (e0 + e1) + (e2 + e3);
                int pk = __builtin_amdgcn_cvt_pk_fp8_f32(e0, e1, 0, false);
                pk = __builtin_amdgcn_cvt_pk_fp8_f32(e2, e3, pk, true);
                *(int*)&attnS8[(16 + lm) * 440 + jt * 16 + quad * 4] = pk;
            }
        }
    }
    s0 += __shfl_xor(s0, 16);
    s0 += __shfl_xor(s0, 32);
    s1 += __shfl_xor(s1, 16);
    s1 += __shfl_xor(s1, 32);
    if (quad == 0) {
        invS[lm]      = (s0 > 0.f) ? (1.f / s0) : 0.f;
        invS[16 + lm] = (s1 > 0.f) ? (1.f / s1) : 0.f;
    }

    // ---- Phase D: nodef [32 x 64] = attn_unnorm @ x (fp8), shared bf ----
    f32x4 na[2][4];
#pragma unroll
    for (int grp = 0; grp < 2; ++grp)
#pragma unroll
        for (int i = 0; i < 4; ++i) na[grp][i] = (f32x4){0.f, 0.f, 0.f, 0.f};
    const char* ar0 = attnS8 + lm * 440 + quad * 8;
    const char* ar1 = attnS8 + (16 + lm) * 440 + quad * 8;
#pragma unroll
    for (int kb = 0; kb < 12; kb += 2) {
        long f00 = *(const long*)(ar0 + kb * 32);
        long f01 = *(const long*)(ar0 + (kb + 1) * 32);
        long f10 = *(const long*)(ar1 + kb * 32);
        long f11 = *(const long*)(ar1 + (kb + 1) * 32);
        long bf[8];
#pragma unroll
        for (int ft = 0; ft < 4; ++ft) {
            bf[ft]     = *(const long*)(xt8b + (kb * 4 + ft) * 512);
            bf[4 + ft] = *(const long*)(xt8b + ((kb + 1) * 4 + ft) * 512);
        }
#pragma unroll
        for (int ft = 0; ft < 4; ++ft) {
            na[0][ft] = __builtin_amdgcn_mfma_f32_16x16x32_fp8_fp8(f00, bf[ft],     na[0][ft], 0, 0, 0);
            na[0][ft] = __builtin_amdgcn_mfma_f32_16x16x32_fp8_fp8(f01, bf[4 + ft], na[0][ft], 0, 0, 0);
            na[1][ft] = __builtin_amdgcn_mfma_f32_16x16x32_fp8_fp8(f10, bf[ft],     na[1][ft], 0, 0, 0);
            na[1][ft] = __builtin_amdgcn_mfma_f32_16x16x32_fp8_fp8(f11, bf[4 + ft], na[1][ft], 0, 0, 0);
        }
    }
    {   // kt = 12 tail
        long f0t = *(const long*)(ar0 + 12 * 32);
        long f1t = *(const long*)(ar1 + 12 * 32);
        long bf[4];
#pragma unroll
        for (int ft = 0; ft < 4; ++ft)
            bf[ft] = *(const long*)(xt8b + (48 + ft) * 512);
#pragma unroll
        for (int ft = 0; ft < 4; ++ft) {
            na[0][ft] = __builtin_amdgcn_mfma_f32_16x16x32_fp8_fp8(f0t, bf[ft], na[0][ft], 0, 0, 0);
            na[1][ft] = __builtin_amdgcn_mfma_f32_16x16x32_fp8_fp8(f1t, bf[ft], na[1][ft], 0, 0, 0);
        }
    }
#pragma unroll
    for (int grp = 0; grp < 2; ++grp)
#pragma unroll
        for (int ft = 0; ft < 4; ++ft)
#pragma unroll
            for (int r = 0; r < 4; ++r)
                featS[(grp * 16 + quad * 4 + r) * 72 + ft * 16 + lm] = f2b(na[grp][ft][r]);

    // ---- Phase E: y [32 x 64] = nodef @ W3, shared wb ----
    f32x4 ya[2][4];
#pragma unroll
    for (int grp = 0; grp < 2; ++grp)
#pragma unroll
        for (int i = 0; i < 4; ++i) ya[grp][i] = (f32x4){0.f, 0.f, 0.f, 0.f};
    short8 n00 = *(const short8*)&featS[lm * 72 + quad * 8];
    short8 n01 = *(const short8*)&featS[lm * 72 + 32 + quad * 8];
    short8 n10 = *(const short8*)&featS[(16 + lm) * 72 + quad * 8];
    short8 n11 = *(const short8*)&featS[(16 + lm) * 72 + 32 + quad * 8];
    {
        short8 wb[8];
#pragma unroll
        for (int ut = 0; ut < 4; ++ut) {
            wb[2 * ut]     = *(const short8*)(W3F + (ut * 2 + 0) * 512 + lane * 8);
            wb[2 * ut + 1] = *(const short8*)(W3F + (ut * 2 + 1) * 512 + lane * 8);
        }
#pragma unroll
        for (int ut = 0; ut < 4; ++ut) {
            ya[0][ut] = __builtin_amdgcn_mfma_f32_16x16x32_bf16(n00, wb[2 * ut],     ya[0][ut], 0, 0, 0);
            ya[0][ut] = __builtin_amdgcn_mfma_f32_16x16x32_bf16(n01, wb[2 * ut + 1], ya[0][ut], 0, 0, 0);
            ya[1][ut] = __builtin_amdgcn_mfma_f32_16x16x32_bf16(n10, wb[2 * ut],     ya[1][ut], 0, 0, 0);
            ya[1][ut] = __builtin_amdgcn_mfma_f32_16x16x32_bf16(n11, wb[2 * ut + 1], ya[1][ut], 0, 0, 0);
        }
    }

    // ---- Epilogue per group: deferred 1/s scale, y store + rhs + r1 ----
    float w3r[4];
#pragma unroll
    for (int ut = 0; ut < 4; ++ut) w3r[ut] = taW3[ut * 16 + lm];
#pragma unroll
    for (int grp = 0; grp < 2; ++grp) {
        int mrb = (g0 + grp) * 16 + quad * 4;           // 4-aligned
        float4 inv4 = *(const float4*)&invS[grp * 16 + quad * 4];
        float invr[4] = {inv4.x, inv4.y, inv4.z, inv4.w};
        float yv[4][4];
#pragma unroll
        for (int ut = 0; ut < 4; ++ut) {
            int u = ut * 16 + lm;
            float b2v = b2p[u];
#pragma unroll
            for (int r = 0; r < 4; ++r) {
                yv[ut][r] = ya[grp][ut][r] * invr[r] + b2v;
                int mrow = mrb + r;
                if (mrow < 400)
                    y[((size_t)bt * 400 + mrow) * 64 + u] = f2b(yv[ut][r]);
            }
        }
        // rhs[bt, mrb+r] = sum_u yv*taW3[u] (reduce over 16 lanes of quad)
        float rv[4];
#pragma unroll
        for (int r = 0; r < 4; ++r) {
            float v = yv[0][r] * w3r[0] + yv[1][r] * w3r[1] +
                      yv[2][r] * w3r[2] + yv[3][r] * w3r[3];
            v += __shfl_xor(v, 1);
            v += __shfl_xor(v, 2);
            v += __shfl_xor(v, 4);
            v += __shfl_xor(v, 8);
            rv[r] = v;
        }
        if (lm == 0 && mrb < 400)
            *(float4*)(rhs + (size_t)bt * 400 + mrb) = make_float4(rv[0], rv[1], rv[2], rv[3]);
        // r1[bt, u] += sum_rows yv*taW1[row] (reduce over quads, atomic)
        float p[4] = {0.f, 0.f, 0.f, 0.f};
#pragma unroll
        for (int r = 0; r < 4; ++r) {
            int mrow = mrb + r;
            if (mrow < 400) {
                float w1v = taW1[mrow];
#pragma unroll
                for (int ut = 0; ut < 4; ++ut) p[ut] += yv[ut][r] * w1v;
            }
        }
#pragma unroll
        for (int ut = 0; ut < 4; ++ut) {
            p[ut] += __shfl_xor(p[ut], 16);
            p[ut] += __shfl_xor(p[ut], 32);
        }
        if (quad == 0) {
#pragma unroll
            for (int ut = 0; ut < 4; ++ut)
                atomicAdd(&r1[bt * 64 + ut * 16 + lm], p[ut]);
        }
    }
}

// ---------------------------------------------------------------------------
// ta_lhs: lhs[bt,n] = sum_f r1[bt,f] * taW2[f,n]
// ---------------------------------------------------------------------------
__global__ __launch_bounds__(256) void ta_lhs(
    const float* __restrict__ r1, const float* __restrict__ taW2,
    float* __restrict__ lhs)
{
    int bt = blockIdx.x, tid = threadIdx.x;
    __shared__ float r1s[64];
    if (tid < 64) r1s[tid] = r1[bt * 64 + tid];
    __syncthreads();
    for (int n = tid; n < 400; n += 256) {
        float acc = 0.f;
#pragma unroll 8
        for (int f = 0; f < 64; ++f) acc += r1s[f] * taW2[f * 400 + n];
        lhs[bt * 400 + n] = acc;
    }
}

// ---------------------------------------------------------------------------
// ta_product: S[b,k,l] = sigmoid( lhs[b,k,:].rhs[b,l,:] + be[k,l] )
// ---------------------------------------------------------------------------
__global__ __launch_bounds__(256) void ta_product(
    const float* __restrict__ lhs, const float* __restrict__ rhs,
    const float* __restrict__ be, float* __restrict__ S)
{
    int kc = blockIdx.x, b = blockIdx.y, tid = threadIdx.x;
    if (tid >= 240) return;
    int k = kc * 4 + tid / 60;
    int l = tid % 60;
    const float4* lr = (const float4*)(lhs + (size_t)(b * 60 + k) * 400);
    const float4* rr = (const float4*)(rhs + (size_t)(b * 60 + l) * 400);
    float acc = 0.f;
    for (int q = 0; q < 100; ++q) {
        float4 a = lr[q], c = rr[q];
        acc += a.x * c.x + a.y * c.y + a.z * c.z + a.w * c.w;
    }
    float v = acc + be[k * 60 + l];
    S[b * 3600 + k * 60 + l] = 1.f / (1.f + __expf(-v));
}

// ---------------------------------------------------------------------------
// ta_softmax: E[b,j,l] = sum_k Ve[j,k]*S[b,k,l]; ker = softmax over j.
// ---------------------------------------------------------------------------
__global__ __launch_bounds__(256) void ta_softmax(
    const float* __restrict__ S, const float* __restrict__ Ve,
    float* __restrict__ ker)
{
    int b = blockIdx.x, tid = threadIdx.x;
    __shared__ float Ss[3600];
    __shared__ float Emat[3600];
    for (int i = tid; i < 3600; i += 256) Ss[i] = S[b * 3600 + i];
    __syncthreads();
    for (int p = tid; p < 3600; p += 256) {
        int j = p / 60, l = p % 60;
        float acc = 0.f;
        for (int k = 0; k < 60; ++k) acc += Ve[j * 60 + k] * Ss[k * 60 + l];
        Emat[p] = acc;
    }
    __syncthreads();
    for (int l = tid; l < 60; l += 256) {
        float mx = -1e30f;
        for (int j = 0; j < 60; ++j) mx = fmaxf(mx, Emat[j * 60 + l]);
        float s = 0.f;
        for (int j = 0; j < 60; ++j) s += __expf(Emat[j * 60 + l] - mx);
        float inv = 1.f / s;
        for (int j = 0; j < 60; ++j)
            ker[b * 3600 + j * 60 + l] = __expf(Emat[j * 60 + l] - mx) * inv;
    }
}

// ---------------------------------------------------------------------------
// ktf_prep: fragment-linear conv weights (unchanged).
// ---------------------------------------------------------------------------
__global__ __launch_bounds__(256) void ktf_prep(
    const float* __restrict__ tk, const float* __restrict__ rk,
    short* __restrict__ KTF)
{
    int i = blockIdx.x * 256 + threadIdx.x;      // [0, 98304)
    int j = i & 7, lane = (i >> 3) & 63, tile = i >> 9;   // tile in [0,192)
    int kkt = tile % 48, ng = tile / 48;
    int u = (ng >> 1) * 32 + (ng & 1) * 16 + (lane & 15);
    int kk = kkt * 32 + (lane >> 4) * 8 + j;
    int dt = kk >> 7, c = kk & 127;
    float v = (c < 64) ? tk[dt * 4096 + c * 64 + u]
                       : rk[dt * 4096 + (c - 64) * 64 + u];
    KTF[i] = f2b(v);
}

// ---------------------------------------------------------------------------
// fused_conv: time-mix + both temporal convs + softplus, bf16 MFMA.
// Conv K-loop batched 2 kkt for load overlap.
// ---------------------------------------------------------------------------
#define IN_S 132
__global__ __launch_bounds__(256, 4) void fused_conv(
    const short* __restrict__ y, const float* __restrict__ ker,
    const float* __restrict__ x, const short* __restrict__ KTF,
    const float* __restrict__ tb, const float* __restrict__ rb,
    float* __restrict__ out)
{
    int n = blockIdx.x, b = blockIdx.y;
    int tid = threadIdx.x, lane = tid & 63, w = tid >> 6;
    int m = lane & 15, quad = lane >> 4;
    int hm = w >> 1, hn = w & 1;

    __shared__ __align__(16) short In[75 * IN_S];
    __shared__ __align__(16) short kerT[64 * 72];
    __shared__ __align__(16) short ybT[64 * 72];

    for (int i = tid; i < 75 * IN_S; i += 256) In[i] = 0;
    for (int i = tid; i < 64 * 72; i += 256) { kerT[i] = 0; ybT[i] = 0; }
    __syncthreads();

    for (int i = tid; i < 3840; i += 256) {
        int t = i >> 6, u = i & 63;
        In[(t + 5) * IN_S + 64 + u] = f2b(x[((size_t)(b * 60 + t) * 400 + n) * 64 + u]);
    }
    for (int i = tid; i < 3840; i += 256) {
        int s = i >> 6, u = i & 63;
        ybT[u * 72 + s] = y[((size_t)(b * 60 + s) * 400 + n) * 64 + u];
    }
    for (int i = tid; i < 3600; i += 256) {
        int s = i / 60, t = i - s * 60;
        kerT[t * 72 + s] = f2b(ker[b * 3600 + s * 60 + t]);
    }
    __syncthreads();

    // ---- time-mix GEMM (M=64,N=64,K=64) ----
    f32x4 tacc[2][2];
#pragma unroll
    for (int a = 0; a < 2; ++a)
#pragma unroll
        for (int c = 0; c < 2; ++c) tacc[a][c] = (f32x4){0.f, 0.f, 0.f, 0.f};
#pragma unroll
    for (int k0 = 0; k0 < 64; k0 += 32) {
        short8 afr[2], bfr[2];
#pragma unroll
        for (int mt = 0; mt < 2; ++mt)
            afr[mt] = *(const short8*)&kerT[(hm * 32 + mt * 16 + m) * 72 + k0 + quad * 8];
#pragma unroll
        for (int nt = 0; nt < 2; ++nt)
            bfr[nt] = *(const short8*)&ybT[(hn * 32 + nt * 16 + m) * 72 + k0 + quad * 8];
#pragma unroll
        for (int mt = 0; mt < 2; ++mt)
#pragma unroll
            for (int nt = 0; nt < 2; ++nt)
                tacc[mt][nt] = __builtin_amdgcn_mfma_f32_16x16x32_bf16(
                    afr[mt], bfr[nt], tacc[mt][nt], 0, 0, 0);
    }
    __syncthreads();

#pragma unroll
    for (int mt = 0; mt < 2; ++mt)
#pragma unroll
        for (int nt = 0; nt < 2; ++nt)
#pragma unroll
            for (int r = 0; r < 4; ++r) {
                int t = hm * 32 + mt * 16 + quad * 4 + r;
                int u = hn * 32 + nt * 16 + m;
                if (t < 60) In[(t + 5) * IN_S + u] = f2b(tacc[mt][nt][r]);
            }
    __syncthreads();

    // ---- conv GEMM (M=64,N=64,K=1536), batched 2 kkt ----
    f32x4 acc[2][2];
#pragma unroll
    for (int a = 0; a < 2; ++a)
#pragma unroll
        for (int c = 0; c < 2; ++c) acc[a][c] = (f32x4){0.f, 0.f, 0.f, 0.f};

    const short* ktf0 = KTF + (size_t)(hn * 2 + 0) * 48 * 512 + lane * 8;
    const short* ktf1 = KTF + (size_t)(hn * 2 + 1) * 48 * 512 + lane * 8;

#pragma unroll 4
    for (int kb = 0; kb < 48; kb += 2) {
        S8u a0[2], a1[2];
        short8 b0[2], b1[2];
#pragma unroll
        for (int q = 0; q < 2; ++q) {
            int kk = (kb + q) * 32;
            int dt = kk >> 7, c0 = (kk & 127) + quad * 8;
            int i0 = (hm * 32 + m + dt) * IN_S + c0;
            int i1 = i0 + 16 * IN_S;
            a0[q].h[0] = *(const short4_t*)&In[i0];
            a0[q].h[1] = *(const short4_t*)&In[i0 + 4];
            a1[q].h[0] = *(const short4_t*)&In[i1];
            a1[q].h[1] = *(const short4_t*)&In[i1 + 4];
            b0[q] = *(const short8*)(ktf0 + (kb + q) * 512);
            b1[q] = *(const short8*)(ktf1 + (kb + q) * 512);
        }
#pragma unroll
        for (int q = 0; q < 2; ++q) {
            acc[0][0] = __builtin_amdgcn_mfma_f32_16x16x32_bf16(a0[q].v, b0[q], acc[0][0], 0, 0, 0);
            acc[0][1] = __builtin_amdgcn_mfma_f32_16x16x32_bf16(a0[q].v, b1[q], acc[0][1], 0, 0, 0);
            acc[1][0] = __builtin_amdgcn_mfma_f32_16x16x32_bf16(a1[q].v, b0[q], acc[1][0], 0, 0, 0);
            acc[1][1] = __builtin_amdgcn_mfma_f32_16x16x32_bf16(a1[q].v, b1[q], acc[1][1], 0, 0, 0);
        }
    }

    float bias[2];
#pragma unroll
    for (int nt = 0; nt < 2; ++nt) {
        int u = hn * 32 + nt * 16 + m;
        bias[nt] = tb[u] + rb[u];
    }
#pragma unroll
    for (int mt = 0; mt < 2; ++mt)
#pragma unroll
        for (int r = 0; r < 4; ++r) {
            int t = hm * 32 + mt * 16 + quad * 4 + r;
            if (t >= 60) continue;
#pragma unroll
            for (int nt = 0; nt < 2; ++nt) {
                int u = hn * 32 + nt * 16 + m;
                float v = acc[mt][nt][r] + bias[nt];
                float sp = fmaxf(v, 0.f) + log1pf(__expf(-fabsf(v)));
                out[((size_t)(b * 60 + t) * 400 + n) * 64 + u] = sp;
            }
        }
}

// ---------------------------------------------------------------------------
extern "C" void kernel_launch(void* const* d_in, const int* in_sizes, int n_in,
                              void* d_out, int out_size, void* d_ws, size_t ws_size,
                              hipStream_t stream)
{
    const float* x    = (const float*)d_in[0];
    const float* A    = (const float*)d_in[1];
    const float* W1   = (const float*)d_in[2];
    const float* W2   = (const float*)d_in[3];
    const float* W3   = (const float*)d_in[4];
    const float* b1   = (const float*)d_in[5];
    const float* b2   = (const float*)d_in[6];
    const float* taW1 = (const float*)d_in[7];
    const float* taW2 = (const float*)d_in[8];
    const float* taW3 = (const float*)d_in[9];
    const float* Ve   = (const float*)d_in[10];
    const float* be   = (const float*)d_in[11];
    const float* tk   = (const float*)d_in[12];
    const float* tb   = (const float*)d_in[13];
    const float* rk   = (const float*)d_in[14];
    const float* rb   = (const float*)d_in[15];
    float* out = (float*)d_out;

    char* wsb = (char*)d_ws;
    size_t off = 0;
    auto alloc = [&](size_t bytes) -> void* {
        void* p = wsb + off;
        off += (bytes + 255) & ~(size_t)255;
        return p;
    };
    short* AWF           = (short*)alloc((size_t)186368 * 2);
    short* W2F           = (short*)alloc((size_t)25600 * 2);
    short* W3F           = (short*)alloc((size_t)4096 * 2);
    unsigned char* Ab2   = (unsigned char*)alloc((size_t)448 * 448);
    short* xF            = (short*)alloc((size_t)480 * 26624 * 2);
    unsigned char* xF8   = (unsigned char*)alloc((size_t)480 * 26624);
    short* y             = (short*)alloc((size_t)480 * 400 * 64 * 2);
    float* r1            = (float*)alloc(480 * 64 * 4);
    float* rhs           = (float*)alloc(480 * 400 * 4);
    float* lhs           = (float*)alloc(480 * 400 * 4);
    float* Sbuf          = (float*)alloc(8 * 3600 * 4);
    float* ker           = (float*)alloc(8 * 3600 * 4);
    short* KTF           = (short*)alloc((size_t)98304 * 2);

    hipMemsetAsync(r1, 0, 480 * 64 * 4, stream);
    prep_w<<<890, 256, 0, stream>>>(A, W1, W2, W3, AWF, W2F, W3F, Ab2);
    prep_xt<<<6240, 256, 0, stream>>>(x, xF, xF8);
    dgc_mfma<<<6720, 64, 0, stream>>>(b1, b2, (const unsigned*)Ab2,
                                      AWF, W2F, W3F, xF, xF8,
                                      taW1, taW3, y, rhs, r1);
    ta_lhs<<<480, 256, 0, stream>>>(r1, taW2, lhs);
    ta_product<<<dim3(15, 8), 256, 0, stream>>>(lhs, rhs, be, Sbuf);
    ta_softmax<<<8, 256, 0, stream>>>(Sbuf, Ve, ker);
    ktf_prep<<<384, 256, 0, stream>>>(tk, rk, KTF);
    fused_conv<<<dim3(400, 8), 256, 0, stream>>>(y, ker, x, KTF, tb, rb, out);
}

// Round 7
// 343.694 us; speedup vs baseline: 1.2938x; 1.1371x over previous
//
#include <hip/hip_runtime.h>
#include <hip/hip_bf16.h>

typedef __attribute__((ext_vector_type(8))) short short8;   // 8 bf16 (4 VGPRs)
typedef __attribute__((ext_vector_type(4))) short short4_t; // 8 B
typedef __attribute__((ext_vector_type(4))) float f32x4;    // MFMA 16x16 acc

union P8u { unsigned char b[8]; long v; };

static __device__ __forceinline__ short f2b(float f) {
    union { float f; unsigned u; } v; v.f = f;
    unsigned r = v.u + 0x7FFFu + ((v.u >> 16) & 1u);   // RNE
    return (short)(r >> 16);
}
static __device__ __forceinline__ unsigned char f2fp8(float f) {
    return (unsigned char)(__builtin_amdgcn_cvt_pk_fp8_f32(f, f, 0, false) & 0xff);
}

// ---------------------------------------------------------------------------
// prep_w: fragment buffers, one THREAD per (tile,lane) -> 8 elems.
//  tiles: [0,364) AWF  (g*13+kt):  A^T*W1^T [m=g*16+lm][n=kt*32+quad*8+j]
//         [364,414) W2F (jt*2+kh): W2[f=kh*32+quad*8+j][jc=jt*16+lm]
//         [414,422) W3F (ut*2+kh): W3[f][u=ut*16+lm]
//  then Ab2[448 m][448 j] bytes = (A[m][j] != 0), zero-padded (m,j >= 400).
// grid 890 x 256 (422*64 + 448*448 = 227712 threads)
// ---------------------------------------------------------------------------
__global__ __launch_bounds__(256) void prep_w(
    const float* __restrict__ A, const float* __restrict__ W1,
    const float* __restrict__ W2, const float* __restrict__ W3,
    short* __restrict__ AWF, short* __restrict__ W2F,
    short* __restrict__ W3F, unsigned char* __restrict__ Ab2)
{
    int t = blockIdx.x * 256 + threadIdx.x;
    if (t < 422 * 64) {
        int tile = t >> 6, lane = t & 63, lm = lane & 15, quad = lane >> 4;
        short8 o;
        if (tile < 364) {
            int kt = tile % 13, g = tile / 13;
            int m = g * 16 + lm;
#pragma unroll
            for (int j = 0; j < 8; ++j) {
                int n = kt * 32 + quad * 8 + j;
                float v = (m < 400 && n < 400) ? A[n * 400 + m] * W1[n * 400 + m] : 0.f;
                o[j] = f2b(v);
            }
            *(short8*)(AWF + tile * 512 + lane * 8) = o;
        } else if (tile < 414) {
            int t2 = tile - 364;
            int kh = t2 & 1, jt = t2 >> 1;
            int jc = jt * 16 + lm;
#pragma unroll
            for (int j = 0; j < 8; ++j) {
                int f = kh * 32 + quad * 8 + j;
                o[j] = f2b(W2[f * 400 + jc]);
            }
            *(short8*)(W2F + t2 * 512 + lane * 8) = o;
        } else {
            int t3 = tile - 414;
            int kh = t3 & 1, ut = t3 >> 1;
            int u = ut * 16 + lm;
#pragma unroll
            for (int j = 0; j < 8; ++j) {
                int f = kh * 32 + quad * 8 + j;
                o[j] = f2b(W3[f * 64 + u]);
            }
            *(short8*)(W3F + t3 * 512 + lane * 8) = o;
        }
    } else {
        int o = t - 27008;
        if (o < 448 * 448) {
            int m = o / 448, j = o - m * 448;
            Ab2[o] = (m < 400 && j < 400 && A[m * 400 + j] != 0.f) ? 1 : 0;
        }
    }
}

// ---------------------------------------------------------------------------
// prep_xt: xF / xF8 fragment-linear, no LDS. One wave per tile; thread
// gathers 8 elems via 8 wave-coalesced dword loads, writes 16B + 8B.
// grid 480*13 blocks; block = (bt, kt), 4 waves = ft 0..3.
// ---------------------------------------------------------------------------
__global__ __launch_bounds__(256) void prep_xt(
    const float* __restrict__ x, short* __restrict__ xF,
    unsigned char* __restrict__ xF8)
{
    int bt = blockIdx.x / 13, kt = blockIdx.x % 13;
    int tid = threadIdx.x, lane = tid & 63, ft = tid >> 6;
    int lm = lane & 15, quad = lane >> 4;
    const float* xs = x + (size_t)bt * 25600;
    int tile = kt * 4 + ft;
    int f = ft * 16 + lm;
    short8 ob; P8u p8;
#pragma unroll
    for (int j = 0; j < 8; ++j) {
        int n = kt * 32 + quad * 8 + j;
        float v = (n < 400) ? xs[(size_t)n * 64 + f] : 0.f;
        ob[j] = f2b(v);
        p8.b[j] = f2fp8(v);
    }
    size_t o = (size_t)bt * 26624 + tile * 512 + lane * 8;
    *(short8*)(xF + o) = ob;
    *(long*)(xF8 + o) = p8.v;
}

// ---------------------------------------------------------------------------
// dgc_mfma v9: 2 ROW-GROUPS PER WAVE (L2-BW fix, confirmed R6: dgc dropped
// 160 -> <134us). Unchanged this round.
// grid 6720 = 8 XCD * 60 bt * 14 group-pairs (XCD-contiguous bt preserved).
// ---------------------------------------------------------------------------
__global__ __launch_bounds__(64) void dgc_mfma(
    const float* __restrict__ b1p, const float* __restrict__ b2p,
    const unsigned* __restrict__ Ab2,
    const short* __restrict__ AWF, const short* __restrict__ W2F,
    const short* __restrict__ W3F, const short* __restrict__ xF,
    const unsigned char* __restrict__ xF8,
    const float* __restrict__ taW1, const float* __restrict__ taW3,
    short* __restrict__ y, float* __restrict__ rhs, float* __restrict__ r1)
{
    int bid = blockIdx.x;
    int c = bid & 7, jj = bid >> 3;     // c = XCD (round-robin), jj in [0,840)
    int bt = c * 60 + jj / 14;          // 60 consecutive bt per XCD
    int gg = jj % 14;                   // pair of 16-row groups: g0=2gg, g1=2gg+1
    int g0 = gg * 2;
    int lane = threadIdx.x;
    int lm = lane & 15, quad = lane >> 4;

    __shared__ __align__(16) char  attnS8[32 * 440];
    __shared__ __align__(16) short featS[32 * 72];
    __shared__ __align__(16) float invS[32];

    {   // zero pad cols [400,440) of both strips (rows lm and 16+lm)
        *(long*)&attnS8[lm * 440 + 400 + quad * 8] = 0;
        *(long*)&attnS8[(16 + lm) * 440 + 400 + quad * 8] = 0;
        if (quad == 0) {
            *(long*)&attnS8[lm * 440 + 432] = 0;
            *(long*)&attnS8[(16 + lm) * 440 + 432] = 0;
        }
    }

    const short* xtb = xF + (size_t)bt * 26624 + lane * 8;
    const unsigned char* xt8b = xF8 + (size_t)bt * 26624 + lane * 8;

    // ---- Phase A: feat [32 x 64] = AWT @ x, 2 groups share the bf loads ----
    f32x4 fa[2][4];
#pragma unroll
    for (int grp = 0; grp < 2; ++grp)
#pragma unroll
        for (int i = 0; i < 4; ++i) fa[grp][i] = (f32x4){0.f, 0.f, 0.f, 0.f};
    const short* awf0 = AWF + (size_t)g0 * 13 * 512 + lane * 8;
    const short* awf1 = awf0 + 13 * 512;
#pragma unroll
    for (int kb = 0; kb < 12; kb += 2) {
        short8 a00 = *(const short8*)(awf0 + kb * 512);
        short8 a01 = *(const short8*)(awf0 + (kb + 1) * 512);
        short8 a10 = *(const short8*)(awf1 + kb * 512);
        short8 a11 = *(const short8*)(awf1 + (kb + 1) * 512);
        short8 bf[8];
#pragma unroll
        for (int ft = 0; ft < 4; ++ft) {
            bf[ft]     = *(const short8*)(xtb + (kb * 4 + ft) * 512);
            bf[4 + ft] = *(const short8*)(xtb + ((kb + 1) * 4 + ft) * 512);
        }
#pragma unroll
        for (int ft = 0; ft < 4; ++ft) {
            fa[0][ft] = __builtin_amdgcn_mfma_f32_16x16x32_bf16(a00, bf[ft],     fa[0][ft], 0, 0, 0);
            fa[0][ft] = __builtin_amdgcn_mfma_f32_16x16x32_bf16(a01, bf[4 + ft], fa[0][ft], 0, 0, 0);
            fa[1][ft] = __builtin_amdgcn_mfma_f32_16x16x32_bf16(a10, bf[ft],     fa[1][ft], 0, 0, 0);
            fa[1][ft] = __builtin_amdgcn_mfma_f32_16x16x32_bf16(a11, bf[4 + ft], fa[1][ft], 0, 0, 0);
        }
    }
    {   // kt = 12 tail
        short8 a0t = *(const short8*)(awf0 + 12 * 512);
        short8 a1t = *(const short8*)(awf1 + 12 * 512);
        short8 bf[4];
#pragma unroll
        for (int ft = 0; ft < 4; ++ft)
            bf[ft] = *(const short8*)(xtb + (48 + ft) * 512);
#pragma unroll
        for (int ft = 0; ft < 4; ++ft) {
            fa[0][ft] = __builtin_amdgcn_mfma_f32_16x16x32_bf16(a0t, bf[ft], fa[0][ft], 0, 0, 0);
            fa[1][ft] = __builtin_amdgcn_mfma_f32_16x16x32_bf16(a1t, bf[ft], fa[1][ft], 0, 0, 0);
        }
    }
#pragma unroll
    for (int grp = 0; grp < 2; ++grp)
#pragma unroll
        for (int ft = 0; ft < 4; ++ft)
#pragma unroll
            for (int r = 0; r < 4; ++r)
                featS[(grp * 16 + quad * 4 + r) * 72 + ft * 16 + lm] = f2b(fa[grp][ft][r]);

    // ---- Phase B (swapped): D' = W2^T @ feat^T, chunked 5 jt, 2 groups ----
    // Lane holds D'[j = jt*16+quad*4+r][m = (g0+grp)*16+lm] = dense[m][j].
    short8 a0g0 = *(const short8*)&featS[lm * 72 + quad * 8];
    short8 a1g0 = *(const short8*)&featS[lm * 72 + 32 + quad * 8];
    short8 a0g1 = *(const short8*)&featS[(16 + lm) * 72 + quad * 8];
    short8 a1g1 = *(const short8*)&featS[(16 + lm) * 72 + 32 + quad * 8];
    int m0 = g0 * 16 + lm;                            // group-0 output row
    const unsigned* ab20 = Ab2 + (size_t)m0 * 112;    // Ab2[m][j] dwords
    const unsigned* ab21 = ab20 + 16 * 112;
    float s0 = 0.f, s1 = 0.f;
#pragma unroll
    for (int jb = 0; jb < 25; jb += 5) {
        short8 bf[10];
#pragma unroll
        for (int q = 0; q < 5; ++q) {
            bf[2 * q]     = *(const short8*)(W2F + ((jb + q) * 2 + 0) * 512 + lane * 8);
            bf[2 * q + 1] = *(const short8*)(W2F + ((jb + q) * 2 + 1) * 512 + lane * 8);
        }
        f32x4 d0[5], d1[5];
#pragma unroll
        for (int q = 0; q < 5; ++q) {
            d0[q] = (f32x4){0.f, 0.f, 0.f, 0.f};
            d0[q] = __builtin_amdgcn_mfma_f32_16x16x32_bf16(bf[2 * q],     a0g0, d0[q], 0, 0, 0);
            d0[q] = __builtin_amdgcn_mfma_f32_16x16x32_bf16(bf[2 * q + 1], a1g0, d0[q], 0, 0, 0);
            d1[q] = (f32x4){0.f, 0.f, 0.f, 0.f};
            d1[q] = __builtin_amdgcn_mfma_f32_16x16x32_bf16(bf[2 * q],     a0g1, d1[q], 0, 0, 0);
            d1[q] = __builtin_amdgcn_mfma_f32_16x16x32_bf16(bf[2 * q + 1], a1g1, d1[q], 0, 0, 0);
        }
#pragma unroll
        for (int q = 0; q < 5; ++q) {
            int jt = jb + q;
            float4 b1v = *(const float4*)(b1p + jt * 16 + quad * 4);
            {
                unsigned mv = ab20[jt * 4 + quad];
                float e0 = (mv & 255u)         ? __expf(d0[q][0] + b1v.x) : 0.f;
                float e1 = ((mv >> 8) & 255u)  ? __expf(d0[q][1] + b1v.y) : 0.f;
                float e2 = ((mv >> 16) & 255u) ? __expf(d0[q][2] + b1v.z) : 0.f;
                float e3 = ((mv >> 24) & 255u) ? __expf(d0[q][3] + b1v.w) : 0.f;
                s0 += (e0 + e1) + (e2 + e3);
                int pk = __builtin_amdgcn_cvt_pk_fp8_f32(e0, e1, 0, false);
                pk = __builtin_amdgcn_cvt_pk_fp8_f32(e2, e3, pk, true);
                *(int*)&attnS8[lm * 440 + jt * 16 + quad * 4] = pk;
            }
            {
                unsigned mv = ab21[jt * 4 + quad];
                float e0 = (mv & 255u)         ? __expf(d1[q][0] + b1v.x) : 0.f;
                float e1 = ((mv >> 8) & 255u)  ? __expf(d1[q][1] + b1v.y) : 0.f;
                float e2 = ((mv >> 16) & 255u) ? __expf(d1[q][2] + b1v.z) : 0.f;
                float e3 = ((mv >> 24) & 255u) ? __expf(d1[q][3] + b1v.w) : 0.f;
                s1 += (e0 + e1) + (e2 + e3);
                int pk = __builtin_amdgcn_cvt_pk_fp8_f32(e0, e1, 0, false);
                pk = __builtin_amdgcn_cvt_pk_fp8_f32(e2, e3, pk, true);
                *(int*)&attnS8[(16 + lm) * 440 + jt * 16 + quad * 4] = pk;
            }
        }
    }
    s0 += __shfl_xor(s0, 16);
    s0 += __shfl_xor(s0, 32);
    s1 += __shfl_xor(s1, 16);
    s1 += __shfl_xor(s1, 32);
    if (quad == 0) {
        invS[lm]      = (s0 > 0.f) ? (1.f / s0) : 0.f;
        invS[16 + lm] = (s1 > 0.f) ? (1.f / s1) : 0.f;
    }

    // ---- Phase D: nodef [32 x 64] = attn_unnorm @ x (fp8), shared bf ----
    f32x4 na[2][4];
#pragma unroll
    for (int grp = 0; grp < 2; ++grp)
#pragma unroll
        for (int i = 0; i < 4; ++i) na[grp][i] = (f32x4){0.f, 0.f, 0.f, 0.f};
    const char* ar0 = attnS8 + lm * 440 + quad * 8;
    const char* ar1 = attnS8 + (16 + lm) * 440 + quad * 8;
#pragma unroll
    for (int kb = 0; kb < 12; kb += 2) {
        long f00 = *(const long*)(ar0 + kb * 32);
        long f01 = *(const long*)(ar0 + (kb + 1) * 32);
        long f10 = *(const long*)(ar1 + kb * 32);
        long f11 = *(const long*)(ar1 + (kb + 1) * 32);
        long bf[8];
#pragma unroll
        for (int ft = 0; ft < 4; ++ft) {
            bf[ft]     = *(const long*)(xt8b + (kb * 4 + ft) * 512);
            bf[4 + ft] = *(const long*)(xt8b + ((kb + 1) * 4 + ft) * 512);
        }
#pragma unroll
        for (int ft = 0; ft < 4; ++ft) {
            na[0][ft] = __builtin_amdgcn_mfma_f32_16x16x32_fp8_fp8(f00, bf[ft],     na[0][ft], 0, 0, 0);
            na[0][ft] = __builtin_amdgcn_mfma_f32_16x16x32_fp8_fp8(f01, bf[4 + ft], na[0][ft], 0, 0, 0);
            na[1][ft] = __builtin_amdgcn_mfma_f32_16x16x32_fp8_fp8(f10, bf[ft],     na[1][ft], 0, 0, 0);
            na[1][ft] = __builtin_amdgcn_mfma_f32_16x16x32_fp8_fp8(f11, bf[4 + ft], na[1][ft], 0, 0, 0);
        }
    }
    {   // kt = 12 tail
        long f0t = *(const long*)(ar0 + 12 * 32);
        long f1t = *(const long*)(ar1 + 12 * 32);
        long bf[4];
#pragma unroll
        for (int ft = 0; ft < 4; ++ft)
            bf[ft] = *(const long*)(xt8b + (48 + ft) * 512);
#pragma unroll
        for (int ft = 0; ft < 4; ++ft) {
            na[0][ft] = __builtin_amdgcn_mfma_f32_16x16x32_fp8_fp8(f0t, bf[ft], na[0][ft], 0, 0, 0);
            na[1][ft] = __builtin_amdgcn_mfma_f32_16x16x32_fp8_fp8(f1t, bf[ft], na[1][ft], 0, 0, 0);
        }
    }
#pragma unroll
    for (int grp = 0; grp < 2; ++grp)
#pragma unroll
        for (int ft = 0; ft < 4; ++ft)
#pragma unroll
            for (int r = 0; r < 4; ++r)
                featS[(grp * 16 + quad * 4 + r) * 72 + ft * 16 + lm] = f2b(na[grp][ft][r]);

    // ---- Phase E: y [32 x 64] = nodef @ W3, shared wb ----
    f32x4 ya[2][4];
#pragma unroll
    for (int grp = 0; grp < 2; ++grp)
#pragma unroll
        for (int i = 0; i < 4; ++i) ya[grp][i] = (f32x4){0.f, 0.f, 0.f, 0.f};
    short8 n00 = *(const short8*)&featS[lm * 72 + quad * 8];
    short8 n01 = *(const short8*)&featS[lm * 72 + 32 + quad * 8];
    short8 n10 = *(const short8*)&featS[(16 + lm) * 72 + quad * 8];
    short8 n11 = *(const short8*)&featS[(16 + lm) * 72 + 32 + quad * 8];
    {
        short8 wb[8];
#pragma unroll
        for (int ut = 0; ut < 4; ++ut) {
            wb[2 * ut]     = *(const short8*)(W3F + (ut * 2 + 0) * 512 + lane * 8);
            wb[2 * ut + 1] = *(const short8*)(W3F + (ut * 2 + 1) * 512 + lane * 8);
        }
#pragma unroll
        for (int ut = 0; ut < 4; ++ut) {
            ya[0][ut] = __builtin_amdgcn_mfma_f32_16x16x32_bf16(n00, wb[2 * ut],     ya[0][ut], 0, 0, 0);
            ya[0][ut] = __builtin_amdgcn_mfma_f32_16x16x32_bf16(n01, wb[2 * ut + 1], ya[0][ut], 0, 0, 0);
            ya[1][ut] = __builtin_amdgcn_mfma_f32_16x16x32_bf16(n10, wb[2 * ut],     ya[1][ut], 0, 0, 0);
            ya[1][ut] = __builtin_amdgcn_mfma_f32_16x16x32_bf16(n11, wb[2 * ut + 1], ya[1][ut], 0, 0, 0);
        }
    }

    // ---- Epilogue per group: deferred 1/s scale, y store + rhs + r1 ----
    float w3r[4];
#pragma unroll
    for (int ut = 0; ut < 4; ++ut) w3r[ut] = taW3[ut * 16 + lm];
#pragma unroll
    for (int grp = 0; grp < 2; ++grp) {
        int mrb = (g0 + grp) * 16 + quad * 4;           // 4-aligned
        float4 inv4 = *(const float4*)&invS[grp * 16 + quad * 4];
        float invr[4] = {inv4.x, inv4.y, inv4.z, inv4.w};
        float yv[4][4];
#pragma unroll
        for (int ut = 0; ut < 4; ++ut) {
            int u = ut * 16 + lm;
            float b2v = b2p[u];
#pragma unroll
            for (int r = 0; r < 4; ++r) {
                yv[ut][r] = ya[grp][ut][r] * invr[r] + b2v;
                int mrow = mrb + r;
                if (mrow < 400)
                    y[((size_t)bt * 400 + mrow) * 64 + u] = f2b(yv[ut][r]);
            }
        }
        // rhs[bt, mrb+r] = sum_u yv*taW3[u] (reduce over 16 lanes of quad)
        float rv[4];
#pragma unroll
        for (int r = 0; r < 4; ++r) {
            float v = yv[0][r] * w3r[0] + yv[1][r] * w3r[1] +
                      yv[2][r] * w3r[2] + yv[3][r] * w3r[3];
            v += __shfl_xor(v, 1);
            v += __shfl_xor(v, 2);
            v += __shfl_xor(v, 4);
            v += __shfl_xor(v, 8);
            rv[r] = v;
        }
        if (lm == 0 && mrb < 400)
            *(float4*)(rhs + (size_t)bt * 400 + mrb) = make_float4(rv[0], rv[1], rv[2], rv[3]);
        // r1[bt, u] += sum_rows yv*taW1[row] (reduce over quads, atomic)
        float p[4] = {0.f, 0.f, 0.f, 0.f};
#pragma unroll
        for (int r = 0; r < 4; ++r) {
            int mrow = mrb + r;
            if (mrow < 400) {
                float w1v = taW1[mrow];
#pragma unroll
                for (int ut = 0; ut < 4; ++ut) p[ut] += yv[ut][r] * w1v;
            }
        }
#pragma unroll
        for (int ut = 0; ut < 4; ++ut) {
            p[ut] += __shfl_xor(p[ut], 16);
            p[ut] += __shfl_xor(p[ut], 32);
        }
        if (quad == 0) {
#pragma unroll
            for (int ut = 0; ut < 4; ++ut)
                atomicAdd(&r1[bt * 64 + ut * 16 + lm], p[ut]);
        }
    }
}

// ---------------------------------------------------------------------------
// ta_lhs: lhs[bt,n] = sum_f r1[bt,f] * taW2[f,n]
// ---------------------------------------------------------------------------
__global__ __launch_bounds__(256) void ta_lhs(
    const float* __restrict__ r1, const float* __restrict__ taW2,
    float* __restrict__ lhs)
{
    int bt = blockIdx.x, tid = threadIdx.x;
    __shared__ float r1s[64];
    if (tid < 64) r1s[tid] = r1[bt * 64 + tid];
    __syncthreads();
    for (int n = tid; n < 400; n += 256) {
        float acc = 0.f;
#pragma unroll 8
        for (int f = 0; f < 64; ++f) acc += r1s[f] * taW2[f * 400 + n];
        lhs[bt * 400 + n] = acc;
    }
}

// ---------------------------------------------------------------------------
// ta_product: S[b,k,l] = sigmoid( lhs[b,k,:].rhs[b,l,:] + be[k,l] )
// ---------------------------------------------------------------------------
__global__ __launch_bounds__(256) void ta_product(
    const float* __restrict__ lhs, const float* __restrict__ rhs,
    const float* __restrict__ be, float* __restrict__ S)
{
    int kc = blockIdx.x, b = blockIdx.y, tid = threadIdx.x;
    if (tid >= 240) return;
    int k = kc * 4 + tid / 60;
    int l = tid % 60;
    const float4* lr = (const float4*)(lhs + (size_t)(b * 60 + k) * 400);
    const float4* rr = (const float4*)(rhs + (size_t)(b * 60 + l) * 400);
    float acc = 0.f;
    for (int q = 0; q < 100; ++q) {
        float4 a = lr[q], c = rr[q];
        acc += a.x * c.x + a.y * c.y + a.z * c.z + a.w * c.w;
    }
    float v = acc + be[k * 60 + l];
    S[b * 3600 + k * 60 + l] = 1.f / (1.f + __expf(-v));
}

// ---------------------------------------------------------------------------
// ta_softmax: E[b,j,l] = sum_k Ve[j,k]*S[b,k,l]; ker = softmax over j.
// ---------------------------------------------------------------------------
__global__ __launch_bounds__(256) void ta_softmax(
    const float* __restrict__ S, const float* __restrict__ Ve,
    float* __restrict__ ker)
{
    int b = blockIdx.x, tid = threadIdx.x;
    __shared__ float Ss[3600];
    __shared__ float Emat[3600];
    for (int i = tid; i < 3600; i += 256) Ss[i] = S[b * 3600 + i];
    __syncthreads();
    for (int p = tid; p < 3600; p += 256) {
        int j = p / 60, l = p % 60;
        float acc = 0.f;
        for (int k = 0; k < 60; ++k) acc += Ve[j * 60 + k] * Ss[k * 60 + l];
        Emat[p] = acc;
    }
    __syncthreads();
    for (int l = tid; l < 60; l += 256) {
        float mx = -1e30f;
        for (int j = 0; j < 60; ++j) mx = fmaxf(mx, Emat[j * 60 + l]);
        float s = 0.f;
        for (int j = 0; j < 60; ++j) s += __expf(Emat[j * 60 + l] - mx);
        float inv = 1.f / s;
        for (int j = 0; j < 60; ++j)
            ker[b * 3600 + j * 60 + l] = __expf(Emat[j * 60 + l] - mx) * inv;
    }
}

// ---------------------------------------------------------------------------
// ktf_prep: fragment-linear conv weights (unchanged).
// ---------------------------------------------------------------------------
__global__ __launch_bounds__(256) void ktf_prep(
    const float* __restrict__ tk, const float* __restrict__ rk,
    short* __restrict__ KTF)
{
    int i = blockIdx.x * 256 + threadIdx.x;      // [0, 98304)
    int j = i & 7, lane = (i >> 3) & 63, tile = i >> 9;   // tile in [0,192)
    int kkt = tile % 48, ng = tile / 48;
    int u = (ng >> 1) * 32 + (ng & 1) * 16 + (lane & 15);
    int kk = kkt * 32 + (lane >> 4) * 8 + j;
    int dt = kk >> 7, c = kk & 127;
    float v = (c < 64) ? tk[dt * 4096 + c * 64 + u]
                       : rk[dt * 4096 + (c - 64) * 64 + u];
    KTF[i] = f2b(v);
}

// ---------------------------------------------------------------------------
// fused_conv v2: VALU diet. R6 counters: VALUBusy 48% vs MfmaUtil 13%,
// HBM 8% -> issue-bound, 7x above both roofline floors. Changes:
//  - IN_S 132->136 (272B rows, 16B-aligned): conv A-operand = 1x ds_read_b128
//    (was 2x 8B, row stride only 8B-aligned). Stride 68 dw -> 2-way = free.
//  - softplus: log1pf (libm, ~25 inst) -> __logf(1+e) (1 hw transcendental).
//  - zero-init only consumed In pad rows (0..4, 65..74) via int stores;
//    kerT/ybT via int4. (was 75 scalar short stores/thread)
//  - x staging: float4 + short4 writes; y staging: short4 reads;
//    ker staging: float4 reads (60=4x15 exact).
//  Bank conflicts (2.64M = 826 cyc/block = 3%) deliberately NOT addressed.
// ---------------------------------------------------------------------------
#define IN_S 136
__global__ __launch_bounds__(256, 4) void fused_conv(
    const short* __restrict__ y, const float* __restrict__ ker,
    const float* __restrict__ x, const short* __restrict__ KTF,
    const float* __restrict__ tb, const float* __restrict__ rb,
    float* __restrict__ out)
{
    int n = blockIdx.x, b = blockIdx.y;
    int tid = threadIdx.x, lane = tid & 63, w = tid >> 6;
    int m = lane & 15, quad = lane >> 4;
    int hm = w >> 1, hn = w & 1;

    __shared__ __align__(16) short In[75 * IN_S];
    __shared__ __align__(16) short kerT[64 * 72];
    __shared__ __align__(16) short ybT[64 * 72];

    {   // zero: In pad rows 0..4 (ints [0,340)) + rows 65..74 (ints [4420,5100))
        for (int i = tid; i < 1020; i += 256) {
            int o = (i < 340) ? i : i + 4080;
            ((int*)In)[o] = 0;
        }
        int4 z4; z4.x = 0; z4.y = 0; z4.z = 0; z4.w = 0;
        for (int i = tid; i < 576; i += 256) {
            ((int4*)kerT)[i] = z4;
            ((int4*)ybT)[i] = z4;
        }
    }
    __syncthreads();

    // x stage: rows 5..64, cols 64..127 (float4 read, short4 write)
    for (int i = tid; i < 960; i += 256) {
        int t = i >> 4, uq = (i & 15) * 4;
        float4 xv = *(const float4*)&x[((size_t)(b * 60 + t) * 400 + n) * 64 + uq];
        short4_t o;
        o[0] = f2b(xv.x); o[1] = f2b(xv.y); o[2] = f2b(xv.z); o[3] = f2b(xv.w);
        *(short4_t*)&In[(t + 5) * IN_S + 64 + uq] = o;
    }
    // y stage: short4 read, transposed scalar writes (8-way bank, ~3% cost)
    for (int i = tid; i < 960; i += 256) {
        int s = i >> 4, uq = (i & 15) * 4;
        short4_t yv = *(const short4_t*)&y[((size_t)(b * 60 + s) * 400 + n) * 64 + uq];
#pragma unroll
        for (int k = 0; k < 4; ++k) ybT[(uq + k) * 72 + s] = yv[k];
    }
    // ker stage: float4 read (60 = 4*15 exact), transposed scalar writes
    for (int i = tid; i < 900; i += 256) {
        int s = i / 15, t4 = (i % 15) * 4;
        float4 kv = *(const float4*)&ker[b * 3600 + s * 60 + t4];
        kerT[(t4 + 0) * 72 + s] = f2b(kv.x);
        kerT[(t4 + 1) * 72 + s] = f2b(kv.y);
        kerT[(t4 + 2) * 72 + s] = f2b(kv.z);
        kerT[(t4 + 3) * 72 + s] = f2b(kv.w);
    }
    __syncthreads();

    // ---- time-mix GEMM (M=64,N=64,K=64) ----
    f32x4 tacc[2][2];
#pragma unroll
    for (int a = 0; a < 2; ++a)
#pragma unroll
        for (int c = 0; c < 2; ++c) tacc[a][c] = (f32x4){0.f, 0.f, 0.f, 0.f};
#pragma unroll
    for (int k0 = 0; k0 < 64; k0 += 32) {
        short8 afr[2], bfr[2];
#pragma unroll
        for (int mt = 0; mt < 2; ++mt)
            afr[mt] = *(const short8*)&kerT[(hm * 32 + mt * 16 + m) * 72 + k0 + quad * 8];
#pragma unroll
        for (int nt = 0; nt < 2; ++nt)
            bfr[nt] = *(const short8*)&ybT[(hn * 32 + nt * 16 + m) * 72 + k0 + quad * 8];
#pragma unroll
        for (int mt = 0; mt < 2; ++mt)
#pragma unroll
            for (int nt = 0; nt < 2; ++nt)
                tacc[mt][nt] = __builtin_amdgcn_mfma_f32_16x16x32_bf16(
                    afr[mt], bfr[nt], tacc[mt][nt], 0, 0, 0);
    }
    __syncthreads();

#pragma unroll
    for (int mt = 0; mt < 2; ++mt)
#pragma unroll
        for (int nt = 0; nt < 2; ++nt)
#pragma unroll
            for (int r = 0; r < 4; ++r) {
                int t = hm * 32 + mt * 16 + quad * 4 + r;
                int u = hn * 32 + nt * 16 + m;
                if (t < 60) In[(t + 5) * IN_S + u] = f2b(tacc[mt][nt][r]);
            }
    __syncthreads();

    // ---- conv GEMM (M=64,N=64,K=1536), batched 2 kkt, b128 A-reads ----
    f32x4 acc[2][2];
#pragma unroll
    for (int a = 0; a < 2; ++a)
#pragma unroll
        for (int c = 0; c < 2; ++c) acc[a][c] = (f32x4){0.f, 0.f, 0.f, 0.f};

    const short* ktf0 = KTF + (size_t)(hn * 2 + 0) * 48 * 512 + lane * 8;
    const short* ktf1 = KTF + (size_t)(hn * 2 + 1) * 48 * 512 + lane * 8;

#pragma unroll 4
    for (int kb = 0; kb < 48; kb += 2) {
        short8 a0[2], a1[2];
        short8 b0[2], b1[2];
#pragma unroll
        for (int q = 0; q < 2; ++q) {
            int kk = (kb + q) * 32;
            int dt = kk >> 7, c0 = (kk & 127) + quad * 8;
            int i0 = (hm * 32 + m + dt) * IN_S + c0;
            a0[q] = *(const short8*)&In[i0];
            a1[q] = *(const short8*)&In[i0 + 16 * IN_S];
            b0[q] = *(const short8*)(ktf0 + (kb + q) * 512);
            b1[q] = *(const short8*)(ktf1 + (kb + q) * 512);
        }
#pragma unroll
        for (int q = 0; q < 2; ++q) {
            acc[0][0] = __builtin_amdgcn_mfma_f32_16x16x32_bf16(a0[q], b0[q], acc[0][0], 0, 0, 0);
            acc[0][1] = __builtin_amdgcn_mfma_f32_16x16x32_bf16(a0[q], b1[q], acc[0][1], 0, 0, 0);
            acc[1][0] = __builtin_amdgcn_mfma_f32_16x16x32_bf16(a1[q], b0[q], acc[1][0], 0, 0, 0);
            acc[1][1] = __builtin_amdgcn_mfma_f32_16x16x32_bf16(a1[q], b1[q], acc[1][1], 0, 0, 0);
        }
    }

    float bias[2];
#pragma unroll
    for (int nt = 0; nt < 2; ++nt) {
        int u = hn * 32 + nt * 16 + m;
        bias[nt] = tb[u] + rb[u];
    }
#pragma unroll
    for (int mt = 0; mt < 2; ++mt)
#pragma unroll
        for (int r = 0; r < 4; ++r) {
            int t = hm * 32 + mt * 16 + quad * 4 + r;
            if (t >= 60) continue;
#pragma unroll
            for (int nt = 0; nt < 2; ++nt) {
                int u = hn * 32 + nt * 16 + m;
                float v = acc[mt][nt][r] + bias[nt];
                float e = __expf(-fabsf(v));
                float sp = fmaxf(v, 0.f) + __logf(1.f + e);
                out[((size_t)(b * 60 + t) * 400 + n) * 64 + u] = sp;
            }
        }
}

// ---------------------------------------------------------------------------
extern "C" void kernel_launch(void* const* d_in, const int* in_sizes, int n_in,
                              void* d_out, int out_size, void* d_ws, size_t ws_size,
                              hipStream_t stream)
{
    const float* x    = (const float*)d_in[0];
    const float* A    = (const float*)d_in[1];
    const float* W1   = (const float*)d_in[2];
    const float* W2   = (const float*)d_in[3];
    const float* W3   = (const float*)d_in[4];
    const float* b1   = (const float*)d_in[5];
    const float* b2   = (const float*)d_in[6];
    const float* taW1 = (const float*)d_in[7];
    const float* taW2 = (const float*)d_in[8];
    const float* taW3 = (const float*)d_in[9];
    const float* Ve   = (const float*)d_in[10];
    const float* be   = (const float*)d_in[11];
    const float* tk   = (const float*)d_in[12];
    const float* tb   = (const float*)d_in[13];
    const float* rk   = (const float*)d_in[14];
    const float* rb   = (const float*)d_in[15];
    float* out = (float*)d_out;

    char* wsb = (char*)d_ws;
    size_t off = 0;
    auto alloc = [&](size_t bytes) -> void* {
        void* p = wsb + off;
        off += (bytes + 255) & ~(size_t)255;
        return p;
    };
    short* AWF           = (short*)alloc((size_t)186368 * 2);
    short* W2F           = (short*)alloc((size_t)25600 * 2);
    short* W3F           = (short*)alloc((size_t)4096 * 2);
    unsigned char* Ab2   = (unsigned char*)alloc((size_t)448 * 448);
    short* xF            = (short*)alloc((size_t)480 * 26624 * 2);
    unsigned char* xF8   = (unsigned char*)alloc((size_t)480 * 26624);
    short* y             = (short*)alloc((size_t)480 * 400 * 64 * 2);
    float* r1            = (float*)alloc(480 * 64 * 4);
    float* rhs           = (float*)alloc(480 * 400 * 4);
    float* lhs           = (float*)alloc(480 * 400 * 4);
    float* Sbuf          = (float*)alloc(8 * 3600 * 4);
    float* ker           = (float*)alloc(8 * 3600 * 4);
    short* KTF           = (short*)alloc((size_t)98304 * 2);

    hipMemsetAsync(r1, 0, 480 * 64 * 4, stream);
    prep_w<<<890, 256, 0, stream>>>(A, W1, W2, W3, AWF, W2F, W3F, Ab2);
    prep_xt<<<6240, 256, 0, stream>>>(x, xF, xF8);
    dgc_mfma<<<6720, 64, 0, stream>>>(b1, b2, (const unsigned*)Ab2,
                                      AWF, W2F, W3F, xF, xF8,
                                      taW1, taW3, y, rhs, r1);
    ta_lhs<<<480, 256, 0, stream>>>(r1, taW2, lhs);
    ta_product<<<dim3(15, 8), 256, 0, stream>>>(lhs, rhs, be, Sbuf);
    ta_softmax<<<8, 256, 0, stream>>>(Sbuf, Ve, ker);
    ktf_prep<<<384, 256, 0, stream>>>(tk, rk, KTF);
    fused_conv<<<dim3(400, 8), 256, 0, stream>>>(y, ker, x, KTF, tb, rb, out);
}